// Round 1
// baseline (454.591 us; speedup 1.0000x reference)
//
#include <hip/hip_runtime.h>
#include <math.h>

#define D 128

// ---------------- CSR build ----------------

__global__ void count_k(const int* __restrict__ dst, int E, int* __restrict__ cnt) {
    int e = blockIdx.x * blockDim.x + threadIdx.x;
    if (e < E) atomicAdd(&cnt[dst[e]], 1);
}

__global__ __launch_bounds__(1024) void scan_a(const int* __restrict__ cnt, int N,
                                               int* __restrict__ part, int* __restrict__ bsum) {
    __shared__ int s[1024];
    int i = blockIdx.x * 1024 + threadIdx.x;
    int v = (i < N) ? cnt[i] : 0;
    s[threadIdx.x] = v;
    __syncthreads();
    for (int off = 1; off < 1024; off <<= 1) {
        int add = (threadIdx.x >= off) ? s[threadIdx.x - off] : 0;
        __syncthreads();
        s[threadIdx.x] += add;
        __syncthreads();
    }
    if (i < N) part[i] = s[threadIdx.x] - v;   // exclusive within chunk
    if (threadIdx.x == 1023) bsum[blockIdx.x] = s[1023];
}

__global__ __launch_bounds__(1024) void scan_b(int* __restrict__ bsum, int nb) {
    __shared__ int s[1024];
    int v = (threadIdx.x < nb) ? bsum[threadIdx.x] : 0;
    s[threadIdx.x] = v;
    __syncthreads();
    for (int off = 1; off < 1024; off <<= 1) {
        int add = (threadIdx.x >= off) ? s[threadIdx.x - off] : 0;
        __syncthreads();
        s[threadIdx.x] += add;
        __syncthreads();
    }
    if (threadIdx.x < nb) bsum[threadIdx.x] = s[threadIdx.x] - v;  // exclusive
}

__global__ void scan_c(const int* __restrict__ cnt, int* __restrict__ part,
                       const int* __restrict__ bsum, int* __restrict__ nextp,
                       float* __restrict__ dinv, int N, int E) {
    int i = blockIdx.x * blockDim.x + threadIdx.x;
    if (i < N) {
        int rp = part[i] + bsum[i >> 10];
        part[i] = rp;        // row_ptr (exclusive scan)
        nextp[i] = rp;       // running fill pointer
        dinv[i] = rsqrtf((float)(cnt[i] + 1));  // +1 self-loop; always > 0
    }
    if (i == 0) part[N] = E;
}

__global__ void fill_k(const int* __restrict__ src, const int* __restrict__ dst, int E,
                       int* __restrict__ nextp, int* __restrict__ ssrc) {
    int e = blockIdx.x * blockDim.x + threadIdx.x;
    if (e < E) {
        int d = dst[e];
        int p = atomicAdd(&nextp[d], 1);
        ssrc[p] = src[e];
    }
}

// ---------------- dense GEMM: H = X @ W  (M x 128 @ 128 x 128, f32) ----------------
// 512 threads, BM=128 rows/block, K staged in chunks of 32.
// thread: cg = t&31 -> 4 cols, rg = t>>5 -> 8 rows; acc 8x4 in regs.

__global__ __launch_bounds__(512) void gemm_k(const float* __restrict__ X,
                                              const float* __restrict__ W,
                                              float* __restrict__ H, int M) {
    __shared__ __align__(16) float Wc[32 * 128];   // [k][c]
    __shared__ __align__(16) float xT[32 * 132];   // [k][r], pad 132 to break bank conflicts
    int t = threadIdx.x;
    int cg = t & 31, rg = t >> 5;
    int c0 = cg * 4, r0 = rg * 8;
    int rowBase = blockIdx.x * 128;

    float4 acc[8];
#pragma unroll
    for (int j = 0; j < 8; ++j) acc[j] = make_float4(0.f, 0.f, 0.f, 0.f);

    for (int kc = 0; kc < 128; kc += 32) {
        // stage W chunk [32][128]: 1024 float4, 2 per thread
        const float4* wg = (const float4*)(W + (size_t)kc * D);
        ((float4*)Wc)[t] = wg[t];
        ((float4*)Wc)[t + 512] = wg[t + 512];
        // stage X chunk transposed: f4 idx f -> row r=f>>3, k-quarter kq=f&7
#pragma unroll
        for (int h = 0; h < 2; ++h) {
            int f = t + h * 512;
            int r = f >> 3, kq = f & 7;
            int gr = rowBase + r;
            float4 xv = make_float4(0.f, 0.f, 0.f, 0.f);
            if (gr < M) xv = *(const float4*)&X[(size_t)gr * D + kc + kq * 4];
            int kb = kq * 4;
            xT[(kb + 0) * 132 + r] = xv.x;
            xT[(kb + 1) * 132 + r] = xv.y;
            xT[(kb + 2) * 132 + r] = xv.z;
            xT[(kb + 3) * 132 + r] = xv.w;
        }
        __syncthreads();
#pragma unroll 8
        for (int k = 0; k < 32; ++k) {
            float4 wv = *(float4*)&Wc[k * 128 + c0];
            float4 xa = *(float4*)&xT[k * 132 + r0];
            float4 xb = *(float4*)&xT[k * 132 + r0 + 4];
            acc[0].x += xa.x * wv.x; acc[0].y += xa.x * wv.y; acc[0].z += xa.x * wv.z; acc[0].w += xa.x * wv.w;
            acc[1].x += xa.y * wv.x; acc[1].y += xa.y * wv.y; acc[1].z += xa.y * wv.z; acc[1].w += xa.y * wv.w;
            acc[2].x += xa.z * wv.x; acc[2].y += xa.z * wv.y; acc[2].z += xa.z * wv.z; acc[2].w += xa.z * wv.w;
            acc[3].x += xa.w * wv.x; acc[3].y += xa.w * wv.y; acc[3].z += xa.w * wv.z; acc[3].w += xa.w * wv.w;
            acc[4].x += xb.x * wv.x; acc[4].y += xb.x * wv.y; acc[4].z += xb.x * wv.z; acc[4].w += xb.x * wv.w;
            acc[5].x += xb.y * wv.x; acc[5].y += xb.y * wv.y; acc[5].z += xb.y * wv.z; acc[5].w += xb.y * wv.w;
            acc[6].x += xb.z * wv.x; acc[6].y += xb.z * wv.y; acc[6].z += xb.z * wv.z; acc[6].w += xb.z * wv.w;
            acc[7].x += xb.w * wv.x; acc[7].y += xb.w * wv.y; acc[7].z += xb.w * wv.z; acc[7].w += xb.w * wv.w;
        }
        __syncthreads();
    }
#pragma unroll
    for (int j = 0; j < 8; ++j) {
        int gr = rowBase + r0 + j;
        if (gr < M) *(float4*)&H[(size_t)gr * D + c0] = acc[j];
    }
}

// ---------------- sparse aggregation: out[n] = b + dinv[n]^2*h[n] + sum_e dinv[s]*dinv[n]*h[s] ----------------
// one wave per node, float2 per lane (128 = 64*2)

__device__ __forceinline__ float gelu_f(float x) {
    return 0.5f * x * (1.0f + erff(x * 0.70710678118654752f));
}

__global__ __launch_bounds__(256) void agg_k(const float* __restrict__ H,
                                             const int* __restrict__ rp,
                                             const int* __restrict__ ssrc,
                                             const float* __restrict__ dinv,
                                             const float* __restrict__ bias,
                                             float* __restrict__ out, int N, int doGelu) {
    int node = blockIdx.x * (blockDim.x >> 6) + (threadIdx.x >> 6);
    int lane = threadIdx.x & 63;
    if (node >= N) return;
    const float2* hb = (const float2*)H;
    float dn = dinv[node];
    float2 hs = hb[(size_t)node * 64 + lane];
    float accx = dn * dn * hs.x;
    float accy = dn * dn * hs.y;
    int e1 = rp[node + 1];
    for (int e = rp[node]; e < e1; ++e) {
        int s = ssrc[e];
        float ns = dinv[s] * dn;
        float2 hv = hb[(size_t)s * 64 + lane];
        accx += ns * hv.x;
        accy += ns * hv.y;
    }
    float2 bv = ((const float2*)bias)[lane];
    accx += bv.x;
    accy += bv.y;
    if (doGelu) { accx = gelu_f(accx); accy = gelu_f(accy); }
    float2 o; o.x = accx; o.y = accy;
    ((float2*)out)[(size_t)node * 64 + lane] = o;
}

// ---------------- launch ----------------

extern "C" void kernel_launch(void* const* d_in, const int* in_sizes, int n_in,
                              void* d_out, int out_size, void* d_ws, size_t ws_size,
                              hipStream_t stream) {
    const float* X  = (const float*)d_in[0];
    const int*   EI = (const int*)d_in[1];
    const float* Wp = (const float*)d_in[2];
    const float* bp = (const float*)d_in[3];
    float* OUT = (float*)d_out;

    int N = in_sizes[0] / D;
    int E = in_sizes[1] / 2;
    int L = in_sizes[3] / D;
    const int* src = EI;
    const int* dst = EI + E;

    char* w = (char*)d_ws;
    auto alloc = [&](size_t bytes) {
        char* p = w;
        w += (bytes + 255) & ~(size_t)255;
        return p;
    };
    float* H    = (float*)alloc((size_t)N * D * sizeof(float));   // 25.6 MB
    float* XB   = (float*)alloc((size_t)N * D * sizeof(float));   // 25.6 MB
    float* DINV = (float*)alloc((size_t)N * sizeof(float));
    int*   RP   = (int*)alloc((size_t)(N + 1) * sizeof(int));
    int*   NXT  = (int*)alloc((size_t)N * sizeof(int));
    int*   CNT  = (int*)alloc((size_t)N * sizeof(int));
    int*   BSUM = (int*)alloc(4096 * sizeof(int));
    int*   SSRC = (int*)alloc((size_t)E * sizeof(int));
    (void)ws_size; (void)n_in; (void)out_size;

    hipMemsetAsync(CNT, 0, (size_t)N * sizeof(int), stream);

    int eb = (E + 255) / 256;
    count_k<<<eb, 256, 0, stream>>>(dst, E, CNT);
    int nb = (N + 1023) / 1024;
    scan_a<<<nb, 1024, 0, stream>>>(CNT, N, RP, BSUM);
    scan_b<<<1, 1024, 0, stream>>>(BSUM, nb);
    scan_c<<<(N + 255) / 256, 256, 0, stream>>>(CNT, RP, BSUM, NXT, DINV, N, E);
    fill_k<<<eb, 256, 0, stream>>>(src, dst, E, NXT, SSRC);

    int gb = (N + 127) / 128;
    int ab = (N + 3) / 4;
    for (int l = 0; l < L; ++l) {
        const float* xin = (l == 0) ? X : XB;
        gemm_k<<<gb, 512, 0, stream>>>(xin, Wp + (size_t)l * D * D, H, N);
        float* o = (l == L - 1) ? OUT : XB;
        agg_k<<<ab, 256, 0, stream>>>(H, RP, SSRC, DINV, bp + (size_t)l * D, o, N,
                                      (l == L - 1) ? 1 : 0);
    }
}

// Round 2
// 366.672 us; speedup vs baseline: 1.2398x; 1.2398x over previous
//
#include <hip/hip_runtime.h>
#include <math.h>

#define D 128

// ---------------- CSR build ----------------

__global__ void count_k(const int* __restrict__ dst, int E, int* __restrict__ cnt) {
    int e = blockIdx.x * blockDim.x + threadIdx.x;
    if (e < E) atomicAdd(&cnt[dst[e]], 1);
}

__global__ __launch_bounds__(1024) void scan_a(const int* __restrict__ cnt, int N,
                                               int* __restrict__ part, int* __restrict__ bsum) {
    __shared__ int s[1024];
    int i = blockIdx.x * 1024 + threadIdx.x;
    int v = (i < N) ? cnt[i] : 0;
    s[threadIdx.x] = v;
    __syncthreads();
    for (int off = 1; off < 1024; off <<= 1) {
        int add = (threadIdx.x >= off) ? s[threadIdx.x - off] : 0;
        __syncthreads();
        s[threadIdx.x] += add;
        __syncthreads();
    }
    if (i < N) part[i] = s[threadIdx.x] - v;   // exclusive within chunk
    if (threadIdx.x == 1023) bsum[blockIdx.x] = s[1023];
}

__global__ __launch_bounds__(1024) void scan_b(int* __restrict__ bsum, int nb) {
    __shared__ int s[1024];
    int v = (threadIdx.x < nb) ? bsum[threadIdx.x] : 0;
    s[threadIdx.x] = v;
    __syncthreads();
    for (int off = 1; off < 1024; off <<= 1) {
        int add = (threadIdx.x >= off) ? s[threadIdx.x - off] : 0;
        __syncthreads();
        s[threadIdx.x] += add;
        __syncthreads();
    }
    if (threadIdx.x < nb) bsum[threadIdx.x] = s[threadIdx.x] - v;  // exclusive
}

__global__ void scan_c(const int* __restrict__ cnt, int* __restrict__ part,
                       const int* __restrict__ bsum, int* __restrict__ nextp,
                       float* __restrict__ dinv, int N, int E) {
    int i = blockIdx.x * blockDim.x + threadIdx.x;
    if (i < N) {
        int rp = part[i] + bsum[i >> 10];
        part[i] = rp;        // row_ptr (exclusive scan)
        nextp[i] = rp;       // running fill pointer
        dinv[i] = rsqrtf((float)(cnt[i] + 1));  // +1 self-loop; always > 0
    }
    if (i == 0) part[N] = E;
}

// fill CSR col indices AND fold the symmetric norm into a per-edge weight,
// removing the dependent dinv[s] load from the aggregation inner loop.
__global__ void fill_k(const int* __restrict__ src, const int* __restrict__ dst, int E,
                       int* __restrict__ nextp, int* __restrict__ ssrc,
                       float* __restrict__ wn, const float* __restrict__ dinv) {
    int e = blockIdx.x * blockDim.x + threadIdx.x;
    if (e < E) {
        int s = src[e];
        int d = dst[e];
        int p = atomicAdd(&nextp[d], 1);
        ssrc[p] = s;
        wn[p] = dinv[s] * dinv[d];
    }
}

// ---------------- dense GEMM: H = X @ W  (M x 128 @ 128 x 128, f32) ----------------

__global__ __launch_bounds__(512) void gemm_k(const float* __restrict__ X,
                                              const float* __restrict__ W,
                                              float* __restrict__ H, int M) {
    __shared__ __align__(16) float Wc[32 * 128];   // [k][c]
    __shared__ __align__(16) float xT[32 * 132];   // [k][r], pad 132 to break bank conflicts
    int t = threadIdx.x;
    int cg = t & 31, rg = t >> 5;
    int c0 = cg * 4, r0 = rg * 8;
    int rowBase = blockIdx.x * 128;

    float4 acc[8];
#pragma unroll
    for (int j = 0; j < 8; ++j) acc[j] = make_float4(0.f, 0.f, 0.f, 0.f);

    for (int kc = 0; kc < 128; kc += 32) {
        const float4* wg = (const float4*)(W + (size_t)kc * D);
        ((float4*)Wc)[t] = wg[t];
        ((float4*)Wc)[t + 512] = wg[t + 512];
#pragma unroll
        for (int h = 0; h < 2; ++h) {
            int f = t + h * 512;
            int r = f >> 3, kq = f & 7;
            int gr = rowBase + r;
            float4 xv = make_float4(0.f, 0.f, 0.f, 0.f);
            if (gr < M) xv = *(const float4*)&X[(size_t)gr * D + kc + kq * 4];
            int kb = kq * 4;
            xT[(kb + 0) * 132 + r] = xv.x;
            xT[(kb + 1) * 132 + r] = xv.y;
            xT[(kb + 2) * 132 + r] = xv.z;
            xT[(kb + 3) * 132 + r] = xv.w;
        }
        __syncthreads();
#pragma unroll 8
        for (int k = 0; k < 32; ++k) {
            float4 wv = *(float4*)&Wc[k * 128 + c0];
            float4 xa = *(float4*)&xT[k * 132 + r0];
            float4 xb = *(float4*)&xT[k * 132 + r0 + 4];
            acc[0].x += xa.x * wv.x; acc[0].y += xa.x * wv.y; acc[0].z += xa.x * wv.z; acc[0].w += xa.x * wv.w;
            acc[1].x += xa.y * wv.x; acc[1].y += xa.y * wv.y; acc[1].z += xa.y * wv.z; acc[1].w += xa.y * wv.w;
            acc[2].x += xa.z * wv.x; acc[2].y += xa.z * wv.y; acc[2].z += xa.z * wv.z; acc[2].w += xa.z * wv.w;
            acc[3].x += xa.w * wv.x; acc[3].y += xa.w * wv.y; acc[3].z += xa.w * wv.z; acc[3].w += xa.w * wv.w;
            acc[4].x += xb.x * wv.x; acc[4].y += xb.x * wv.y; acc[4].z += xb.x * wv.z; acc[4].w += xb.x * wv.w;
            acc[5].x += xb.y * wv.x; acc[5].y += xb.y * wv.y; acc[5].z += xb.y * wv.z; acc[5].w += xb.y * wv.w;
            acc[6].x += xb.z * wv.x; acc[6].y += xb.z * wv.y; acc[6].z += xb.z * wv.z; acc[6].w += xb.z * wv.w;
            acc[7].x += xb.w * wv.x; acc[7].y += xb.w * wv.y; acc[7].z += xb.w * wv.z; acc[7].w += xb.w * wv.w;
        }
        __syncthreads();
    }
#pragma unroll
    for (int j = 0; j < 8; ++j) {
        int gr = rowBase + r0 + j;
        if (gr < M) *(float4*)&H[(size_t)gr * D + c0] = acc[j];
    }
}

// ---------------- sparse aggregation ----------------
// out[n] = b + dinv[n]^2*h[n] + sum_e wn[e]*h[ssrc[e]]
// one wave per node, float2 per lane; 4x manual unroll -> 4 row-gathers in flight.

__device__ __forceinline__ float gelu_f(float x) {
    return 0.5f * x * (1.0f + erff(x * 0.70710678118654752f));
}

__global__ __launch_bounds__(256) void agg_k(const float* __restrict__ H,
                                             const int* __restrict__ rp,
                                             const int* __restrict__ ssrc,
                                             const float* __restrict__ wn,
                                             const float* __restrict__ dinv,
                                             const float* __restrict__ bias,
                                             float* __restrict__ out, int N, int doGelu) {
    int node = blockIdx.x * (blockDim.x >> 6) + (threadIdx.x >> 6);
    int lane = threadIdx.x & 63;
    if (node >= N) return;
    const float2* __restrict__ hb = (const float2*)H;
    float dn = dinv[node];
    float2 hs = hb[(size_t)node * 64 + lane];
    float ax = dn * dn * hs.x;
    float ay = dn * dn * hs.y;
    float bx2 = 0.f, by2 = 0.f;
    int e = rp[node];
    int e1 = rp[node + 1];
    for (; e + 4 <= e1; e += 4) {
        int s0 = ssrc[e + 0];
        int s1 = ssrc[e + 1];
        int s2 = ssrc[e + 2];
        int s3 = ssrc[e + 3];
        float w0 = wn[e + 0];
        float w1 = wn[e + 1];
        float w2 = wn[e + 2];
        float w3 = wn[e + 3];
        float2 h0 = hb[(size_t)s0 * 64 + lane];
        float2 h1 = hb[(size_t)s1 * 64 + lane];
        float2 h2 = hb[(size_t)s2 * 64 + lane];
        float2 h3 = hb[(size_t)s3 * 64 + lane];
        ax += w0 * h0.x; ay += w0 * h0.y;
        bx2 += w1 * h1.x; by2 += w1 * h1.y;
        ax += w2 * h2.x; ay += w2 * h2.y;
        bx2 += w3 * h3.x; by2 += w3 * h3.y;
    }
    for (; e < e1; ++e) {
        int s = ssrc[e];
        float w = wn[e];
        float2 hv = hb[(size_t)s * 64 + lane];
        ax += w * hv.x; ay += w * hv.y;
    }
    ax += bx2; ay += by2;
    float2 bv = ((const float2*)bias)[lane];
    ax += bv.x; ay += bv.y;
    if (doGelu) { ax = gelu_f(ax); ay = gelu_f(ay); }
    ((float2*)out)[(size_t)node * 64 + lane] = make_float2(ax, ay);
}

// ---------------- launch ----------------

extern "C" void kernel_launch(void* const* d_in, const int* in_sizes, int n_in,
                              void* d_out, int out_size, void* d_ws, size_t ws_size,
                              hipStream_t stream) {
    const float* X  = (const float*)d_in[0];
    const int*   EI = (const int*)d_in[1];
    const float* Wp = (const float*)d_in[2];
    const float* bp = (const float*)d_in[3];
    float* OUT = (float*)d_out;

    int N = in_sizes[0] / D;
    int E = in_sizes[1] / 2;
    int L = in_sizes[3] / D;
    const int* src = EI;
    const int* dst = EI + E;

    char* w = (char*)d_ws;
    auto alloc = [&](size_t bytes) {
        char* p = w;
        w += (bytes + 255) & ~(size_t)255;
        return p;
    };
    float* H    = (float*)alloc((size_t)N * D * sizeof(float));   // 25.6 MB
    float* XB   = (float*)alloc((size_t)N * D * sizeof(float));   // 25.6 MB
    float* DINV = (float*)alloc((size_t)N * sizeof(float));
    int*   RP   = (int*)alloc((size_t)(N + 1) * sizeof(int));
    int*   NXT  = (int*)alloc((size_t)N * sizeof(int));
    int*   CNT  = (int*)alloc((size_t)N * sizeof(int));
    int*   BSUM = (int*)alloc(4096 * sizeof(int));
    int*   SSRC = (int*)alloc((size_t)E * sizeof(int));
    float* WN   = (float*)alloc((size_t)E * sizeof(float));
    (void)ws_size; (void)n_in; (void)out_size;

    hipMemsetAsync(CNT, 0, (size_t)N * sizeof(int), stream);

    int eb = (E + 255) / 256;
    count_k<<<eb, 256, 0, stream>>>(dst, E, CNT);
    int nb = (N + 1023) / 1024;
    scan_a<<<nb, 1024, 0, stream>>>(CNT, N, RP, BSUM);
    scan_b<<<1, 1024, 0, stream>>>(BSUM, nb);
    scan_c<<<(N + 255) / 256, 256, 0, stream>>>(CNT, RP, BSUM, NXT, DINV, N, E);
    fill_k<<<eb, 256, 0, stream>>>(src, dst, E, NXT, SSRC, WN, DINV);

    int gb = (N + 127) / 128;
    int ab = (N + 3) / 4;
    for (int l = 0; l < L; ++l) {
        const float* xin = (l == 0) ? X : XB;
        gemm_k<<<gb, 512, 0, stream>>>(xin, Wp + (size_t)l * D * D, H, N);
        float* o = (l == L - 1) ? OUT : XB;
        agg_k<<<ab, 256, 0, stream>>>(H, RP, SSRC, WN, DINV, bp + (size_t)l * D, o, N,
                                      (l == L - 1) ? 1 : 0);
    }
}

// Round 3
// 282.590 us; speedup vs baseline: 1.6087x; 1.2975x over previous
//
#include <hip/hip_runtime.h>
#include <math.h>

#define D 128

typedef __attribute__((ext_vector_type(8))) short short8v;
typedef __attribute__((ext_vector_type(4))) float f32x4;

__device__ __forceinline__ unsigned short f2bf(float x) {
    unsigned int u = __float_as_uint(x);
    unsigned int r = (u + 0x7FFFu + ((u >> 16) & 1u)) >> 16;
    return (unsigned short)r;
}
__device__ __forceinline__ float bf2f(unsigned short b) {
    return __uint_as_float(((unsigned int)b) << 16);
}

// ---------------- CSR build ----------------

__global__ void count_k(const int* __restrict__ dst, int E, int* __restrict__ cnt) {
    int e = blockIdx.x * blockDim.x + threadIdx.x;
    if (e < E) atomicAdd(&cnt[dst[e]], 1);
}

__global__ __launch_bounds__(1024) void scan_a(const int* __restrict__ cnt, int N,
                                               int* __restrict__ part, int* __restrict__ bsum) {
    __shared__ int s[1024];
    int i = blockIdx.x * 1024 + threadIdx.x;
    int v = (i < N) ? cnt[i] : 0;
    s[threadIdx.x] = v;
    __syncthreads();
    for (int off = 1; off < 1024; off <<= 1) {
        int add = (threadIdx.x >= off) ? s[threadIdx.x - off] : 0;
        __syncthreads();
        s[threadIdx.x] += add;
        __syncthreads();
    }
    if (i < N) part[i] = s[threadIdx.x] - v;   // exclusive within chunk
    if (threadIdx.x == 1023) bsum[blockIdx.x] = s[1023];
}

__global__ __launch_bounds__(1024) void scan_b(int* __restrict__ bsum, int nb) {
    __shared__ int s[1024];
    int v = (threadIdx.x < nb) ? bsum[threadIdx.x] : 0;
    s[threadIdx.x] = v;
    __syncthreads();
    for (int off = 1; off < 1024; off <<= 1) {
        int add = (threadIdx.x >= off) ? s[threadIdx.x - off] : 0;
        __syncthreads();
        s[threadIdx.x] += add;
        __syncthreads();
    }
    if (threadIdx.x < nb) bsum[threadIdx.x] = s[threadIdx.x] - v;  // exclusive
}

__global__ void scan_c(const int* __restrict__ cnt, int* __restrict__ part,
                       const int* __restrict__ bsum, int* __restrict__ nextp,
                       float* __restrict__ dinv, int N, int E) {
    int i = blockIdx.x * blockDim.x + threadIdx.x;
    if (i < N) {
        int rp = part[i] + bsum[i >> 10];
        part[i] = rp;
        nextp[i] = rp;
        dinv[i] = rsqrtf((float)(cnt[i] + 1));  // +1 self-loop; always > 0
    }
    if (i == 0) part[N] = E;
}

__global__ void fill_k(const int* __restrict__ src, const int* __restrict__ dst, int E,
                       int* __restrict__ nextp, int* __restrict__ ssrc,
                       float* __restrict__ wn, const float* __restrict__ dinv) {
    int e = blockIdx.x * blockDim.x + threadIdx.x;
    if (e < E) {
        int s = src[e];
        int d = dst[e];
        int p = atomicAdd(&nextp[d], 1);
        ssrc[p] = s;
        wn[p] = dinv[s] * dinv[d];
    }
}

// ---------------- W split: frag-ordered hi/lo bf16 ----------------
// BF[l][ks][ct][lane][i] = bf16split(W[l][ks*32 + (lane>>4)*8 + i][ct*16 + (lane&15)])

__global__ void wsplit_k(const float* __restrict__ Wp, short* __restrict__ BFh,
                         short* __restrict__ BFl, int total) {
    int idx = blockIdx.x * blockDim.x + threadIdx.x;
    if (idx >= total) return;
    int i    = idx & 7;
    int lane = (idx >> 3) & 63;
    int ct   = (idx >> 9) & 7;
    int ks   = (idx >> 12) & 3;
    int l    = idx >> 14;
    int k = ks * 32 + (lane >> 4) * 8 + i;
    int n = ct * 16 + (lane & 15);
    float w = Wp[(size_t)l * (D * D) + (size_t)k * D + n];
    unsigned short h = f2bf(w);
    float lo = w - bf2f(h);
    BFh[idx] = (short)h;
    BFl[idx] = (short)f2bf(lo);
}

// ---------------- GEMM: Hb(bf16) = X(f32) @ W, split-bf16 MFMA ----------------
// 256 thr = 4 waves; wave handles 16 rows x 128 cols; 96 MFMA/wave; no LDS.

__global__ __launch_bounds__(256) void gemm_k(const float* __restrict__ X,
                                              const short* __restrict__ BFh,
                                              const short* __restrict__ BFl,
                                              unsigned short* __restrict__ Hb, int M) {
    int lane = threadIdx.x & 63;
    int wv = threadIdx.x >> 6;
    int rowBase = blockIdx.x * 64 + wv * 16;
    int arow = rowBase + (lane & 15);
    bool aval = arow < M;
    const float* xr = X + (size_t)arow * D + (lane >> 4) * 8;

    short8v ah[4], al[4];
#pragma unroll
    for (int ks = 0; ks < 4; ++ks) {
        float4 p = make_float4(0.f, 0.f, 0.f, 0.f);
        float4 q = make_float4(0.f, 0.f, 0.f, 0.f);
        if (aval) {
            p = *(const float4*)(xr + ks * 32);
            q = *(const float4*)(xr + ks * 32 + 4);
        }
        float v[8] = {p.x, p.y, p.z, p.w, q.x, q.y, q.z, q.w};
#pragma unroll
        for (int i = 0; i < 8; ++i) {
            unsigned short h = f2bf(v[i]);
            ah[ks][i] = (short)h;
            al[ks][i] = (short)f2bf(v[i] - bf2f(h));
        }
    }

    const short8v* Bh = (const short8v*)BFh;
    const short8v* Bl = (const short8v*)BFl;
#pragma unroll
    for (int ct = 0; ct < 8; ++ct) {
        short8v bh[4], bl[4];
#pragma unroll
        for (int ks = 0; ks < 4; ++ks) {
            bh[ks] = Bh[(ks * 8 + ct) * 64 + lane];
            bl[ks] = Bl[(ks * 8 + ct) * 64 + lane];
        }
        f32x4 acc = {0.f, 0.f, 0.f, 0.f};
#pragma unroll
        for (int ks = 0; ks < 4; ++ks) {
            acc = __builtin_amdgcn_mfma_f32_16x16x32_bf16(ah[ks], bh[ks], acc, 0, 0, 0);
            acc = __builtin_amdgcn_mfma_f32_16x16x32_bf16(al[ks], bh[ks], acc, 0, 0, 0);
            acc = __builtin_amdgcn_mfma_f32_16x16x32_bf16(ah[ks], bl[ks], acc, 0, 0, 0);
        }
        int c = ct * 16 + (lane & 15);
        int rb = rowBase + (lane >> 4) * 4;
#pragma unroll
        for (int i = 0; i < 4; ++i) {
            int r = rb + i;
            if (r < M) Hb[(size_t)r * D + c] = f2bf(acc[i]);
        }
    }
}

// ---------------- sparse aggregation (bf16 H gathers) ----------------
// out[n] = b + dinv[n]^2*h[n] + sum_e wn[e]*h[ssrc[e]]; wave/node, uint (2xbf16)/lane.

__device__ __forceinline__ float gelu_f(float x) {
    return 0.5f * x * (1.0f + erff(x * 0.70710678118654752f));
}

__global__ __launch_bounds__(256) void agg_k(const unsigned short* __restrict__ Hb,
                                             const int* __restrict__ rp,
                                             const int* __restrict__ ssrc,
                                             const float* __restrict__ wn,
                                             const float* __restrict__ dinv,
                                             const float* __restrict__ bias,
                                             float* __restrict__ out, int N, int doGelu) {
    int node = blockIdx.x * 4 + (threadIdx.x >> 6);
    int lane = threadIdx.x & 63;
    if (node >= N) return;
    const unsigned int* __restrict__ hb = (const unsigned int*)Hb;
    float dn = dinv[node];
    unsigned int sv = hb[(size_t)node * 64 + lane];
    float ax = dn * dn * __uint_as_float(sv << 16);
    float ay = dn * dn * __uint_as_float(sv & 0xFFFF0000u);
    float bx = 0.f, by = 0.f;
    int e = rp[node];
    int e1 = rp[node + 1];
    for (; e + 8 <= e1; e += 8) {
        int s[8];
        float ww[8];
        unsigned int v[8];
#pragma unroll
        for (int j = 0; j < 8; ++j) s[j] = ssrc[e + j];
#pragma unroll
        for (int j = 0; j < 8; ++j) ww[j] = wn[e + j];
#pragma unroll
        for (int j = 0; j < 8; ++j) v[j] = hb[(size_t)s[j] * 64 + lane];
#pragma unroll
        for (int j = 0; j < 8; ++j) {
            float fx = __uint_as_float(v[j] << 16);
            float fy = __uint_as_float(v[j] & 0xFFFF0000u);
            if (j & 1) { bx += ww[j] * fx; by += ww[j] * fy; }
            else       { ax += ww[j] * fx; ay += ww[j] * fy; }
        }
    }
    for (; e < e1; ++e) {
        int s = ssrc[e];
        float w = wn[e];
        unsigned int v = hb[(size_t)s * 64 + lane];
        ax += w * __uint_as_float(v << 16);
        ay += w * __uint_as_float(v & 0xFFFF0000u);
    }
    ax += bx; ay += by;
    float2 bv = ((const float2*)bias)[lane];
    ax += bv.x; ay += bv.y;
    if (doGelu) { ax = gelu_f(ax); ay = gelu_f(ay); }
    ((float2*)out)[(size_t)node * 64 + lane] = make_float2(ax, ay);
}

// ---------------- launch ----------------

extern "C" void kernel_launch(void* const* d_in, const int* in_sizes, int n_in,
                              void* d_out, int out_size, void* d_ws, size_t ws_size,
                              hipStream_t stream) {
    const float* X  = (const float*)d_in[0];
    const int*   EI = (const int*)d_in[1];
    const float* Wp = (const float*)d_in[2];
    const float* bp = (const float*)d_in[3];
    float* OUT = (float*)d_out;

    int N = in_sizes[0] / D;
    int E = in_sizes[1] / 2;
    int L = in_sizes[3] / D;
    const int* src = EI;
    const int* dst = EI + E;

    char* w = (char*)d_ws;
    auto alloc = [&](size_t bytes) {
        char* p = w;
        w += (bytes + 255) & ~(size_t)255;
        return p;
    };
    unsigned short* HB = (unsigned short*)alloc((size_t)N * D * sizeof(unsigned short)); // 12.8 MB
    float* XB   = (float*)alloc((size_t)N * D * sizeof(float));   // 25.6 MB
    float* DINV = (float*)alloc((size_t)N * sizeof(float));
    int*   RP   = (int*)alloc((size_t)(N + 1) * sizeof(int));
    int*   NXT  = (int*)alloc((size_t)N * sizeof(int));
    int*   CNT  = (int*)alloc((size_t)N * sizeof(int));
    int*   BSUM = (int*)alloc(4096 * sizeof(int));
    int*   SSRC = (int*)alloc((size_t)E * sizeof(int));
    float* WN   = (float*)alloc((size_t)E * sizeof(float));
    short* BFH  = (short*)alloc((size_t)L * D * D * sizeof(short));
    short* BFL  = (short*)alloc((size_t)L * D * D * sizeof(short));
    (void)ws_size; (void)n_in; (void)out_size;

    hipMemsetAsync(CNT, 0, (size_t)N * sizeof(int), stream);

    int eb = (E + 255) / 256;
    count_k<<<eb, 256, 0, stream>>>(dst, E, CNT);
    int nb = (N + 1023) / 1024;
    scan_a<<<nb, 1024, 0, stream>>>(CNT, N, RP, BSUM);
    scan_b<<<1, 1024, 0, stream>>>(BSUM, nb);
    scan_c<<<(N + 255) / 256, 256, 0, stream>>>(CNT, RP, BSUM, NXT, DINV, N, E);
    fill_k<<<eb, 256, 0, stream>>>(src, dst, E, NXT, SSRC, WN, DINV);

    int wtot = L * D * D;
    wsplit_k<<<(wtot + 255) / 256, 256, 0, stream>>>(Wp, BFH, BFL, wtot);

    int gb = (N + 63) / 64;
    int ab = (N + 3) / 4;
    for (int l = 0; l < L; ++l) {
        const float* xin = (l == 0) ? X : XB;
        gemm_k<<<gb, 256, 0, stream>>>(xin, BFH + (size_t)l * D * D, BFL + (size_t)l * D * D, HB, N);
        float* o = (l == L - 1) ? OUT : XB;
        agg_k<<<ab, 256, 0, stream>>>(HB, RP, SSRC, WN, DINV, bp + (size_t)l * D, o, N,
                                      (l == L - 1) ? 1 : 0);
    }
}

// Round 4
// 236.683 us; speedup vs baseline: 1.9207x; 1.1940x over previous
//
#include <hip/hip_runtime.h>
#include <math.h>

#define D 128

typedef __attribute__((ext_vector_type(8))) short short8v;
typedef __attribute__((ext_vector_type(4))) float f32x4;

__device__ __forceinline__ unsigned short f2bf(float x) {
    unsigned int u = __float_as_uint(x);
    unsigned int r = (u + 0x7FFFu + ((u >> 16) & 1u)) >> 16;
    return (unsigned short)r;
}
__device__ __forceinline__ float bf2f(unsigned short b) {
    return __uint_as_float(((unsigned int)b) << 16);
}

// ---------------- CSR build ----------------
// rank_k: per-edge arrival rank among same-dst edges (atomic WITH return —
// this pass already pays the atomic, so capture the rank here and make the
// fill pass atomic-free).

__global__ void rank_k(const int* __restrict__ dst, int E,
                       int* __restrict__ cnt, int* __restrict__ rank) {
    int e = blockIdx.x * blockDim.x + threadIdx.x;
    if (e < E) rank[e] = atomicAdd(&cnt[dst[e]], 1);
}

__global__ __launch_bounds__(1024) void scan_a(const int* __restrict__ cnt, int N,
                                               int* __restrict__ part, int* __restrict__ bsum) {
    __shared__ int s[1024];
    int i = blockIdx.x * 1024 + threadIdx.x;
    int v = (i < N) ? cnt[i] : 0;
    s[threadIdx.x] = v;
    __syncthreads();
    for (int off = 1; off < 1024; off <<= 1) {
        int add = (threadIdx.x >= off) ? s[threadIdx.x - off] : 0;
        __syncthreads();
        s[threadIdx.x] += add;
        __syncthreads();
    }
    if (i < N) part[i] = s[threadIdx.x] - v;   // exclusive within chunk
    if (threadIdx.x == 1023) bsum[blockIdx.x] = s[1023];
}

__global__ __launch_bounds__(1024) void scan_b(int* __restrict__ bsum, int nb) {
    __shared__ int s[1024];
    int v = (threadIdx.x < nb) ? bsum[threadIdx.x] : 0;
    s[threadIdx.x] = v;
    __syncthreads();
    for (int off = 1; off < 1024; off <<= 1) {
        int add = (threadIdx.x >= off) ? s[threadIdx.x - off] : 0;
        __syncthreads();
        s[threadIdx.x] += add;
        __syncthreads();
    }
    if (threadIdx.x < nb) bsum[threadIdx.x] = s[threadIdx.x] - v;  // exclusive
}

__global__ void scan_c(const int* __restrict__ cnt, int* __restrict__ part,
                       const int* __restrict__ bsum,
                       float* __restrict__ dinv, int N, int E) {
    int i = blockIdx.x * blockDim.x + threadIdx.x;
    if (i < N) {
        part[i] = part[i] + bsum[i >> 10];       // row_ptr (exclusive scan)
        dinv[i] = rsqrtf((float)(cnt[i] + 1));   // +1 self-loop; always > 0
    }
    if (i == 0) part[N] = E;
}

// atomic-free fill: position = row_ptr[dst] + rank. ushort col index (N < 65536).
__global__ void fill_k(const int* __restrict__ src, const int* __restrict__ dst,
                       const int* __restrict__ rank, const int* __restrict__ rp,
                       int E, unsigned short* __restrict__ ssrc) {
    int e = blockIdx.x * blockDim.x + threadIdx.x;
    if (e < E) {
        int p = rp[dst[e]] + rank[e];
        ssrc[p] = (unsigned short)src[e];
    }
}

// ---------------- W split: frag-ordered hi/lo bf16 ----------------
// BF[l][ks][ct][lane][i] = bf16split(W[l][ks*32 + (lane>>4)*8 + i][ct*16 + (lane&15)])

__global__ void wsplit_k(const float* __restrict__ Wp, short* __restrict__ BFh,
                         short* __restrict__ BFl, int total) {
    int idx = blockIdx.x * blockDim.x + threadIdx.x;
    if (idx >= total) return;
    int i    = idx & 7;
    int lane = (idx >> 3) & 63;
    int ct   = (idx >> 9) & 7;
    int ks   = (idx >> 12) & 3;
    int l    = idx >> 14;
    int k = ks * 32 + (lane >> 4) * 8 + i;
    int n = ct * 16 + (lane & 15);
    float w = Wp[(size_t)l * (D * D) + (size_t)k * D + n];
    unsigned short h = f2bf(w);
    float lo = w - bf2f(h);
    BFh[idx] = (short)h;
    BFl[idx] = (short)f2bf(lo);
}

// ---------------- GEMM: Hb(bf16) = diag(dinv) * (X(f32) @ W), split-bf16 MFMA ----
// 256 thr = 4 waves; wave handles 16 rows x 128 cols; 96 MFMA/wave; no LDS.

__global__ __launch_bounds__(256) void gemm_k(const float* __restrict__ X,
                                              const short* __restrict__ BFh,
                                              const short* __restrict__ BFl,
                                              const float* __restrict__ dinv,
                                              unsigned short* __restrict__ Hb, int M) {
    int lane = threadIdx.x & 63;
    int wv = threadIdx.x >> 6;
    int rowBase = blockIdx.x * 64 + wv * 16;
    int arow = rowBase + (lane & 15);
    bool aval = arow < M;
    const float* xr = X + (size_t)arow * D + (lane >> 4) * 8;

    short8v ah[4], al[4];
#pragma unroll
    for (int ks = 0; ks < 4; ++ks) {
        float4 p = make_float4(0.f, 0.f, 0.f, 0.f);
        float4 q = make_float4(0.f, 0.f, 0.f, 0.f);
        if (aval) {
            p = *(const float4*)(xr + ks * 32);
            q = *(const float4*)(xr + ks * 32 + 4);
        }
        float v[8] = {p.x, p.y, p.z, p.w, q.x, q.y, q.z, q.w};
#pragma unroll
        for (int i = 0; i < 8; ++i) {
            unsigned short h = f2bf(v[i]);
            ah[ks][i] = (short)h;
            al[ks][i] = (short)f2bf(v[i] - bf2f(h));
        }
    }

    // per-lane row scales for the 4 output rows this lane owns
    int rb = rowBase + (lane >> 4) * 4;
    float dsc[4];
#pragma unroll
    for (int i = 0; i < 4; ++i) dsc[i] = (rb + i < M) ? dinv[rb + i] : 0.f;

    const short8v* Bh = (const short8v*)BFh;
    const short8v* Bl = (const short8v*)BFl;
#pragma unroll
    for (int ct = 0; ct < 8; ++ct) {
        short8v bh[4], bl[4];
#pragma unroll
        for (int ks = 0; ks < 4; ++ks) {
            bh[ks] = Bh[(ks * 8 + ct) * 64 + lane];
            bl[ks] = Bl[(ks * 8 + ct) * 64 + lane];
        }
        f32x4 acc = {0.f, 0.f, 0.f, 0.f};
#pragma unroll
        for (int ks = 0; ks < 4; ++ks) {
            acc = __builtin_amdgcn_mfma_f32_16x16x32_bf16(ah[ks], bh[ks], acc, 0, 0, 0);
            acc = __builtin_amdgcn_mfma_f32_16x16x32_bf16(al[ks], bh[ks], acc, 0, 0, 0);
            acc = __builtin_amdgcn_mfma_f32_16x16x32_bf16(ah[ks], bl[ks], acc, 0, 0, 0);
        }
        int c = ct * 16 + (lane & 15);
#pragma unroll
        for (int i = 0; i < 4; ++i) {
            int r = rb + i;
            if (r < M) Hb[(size_t)r * D + c] = f2bf(dsc[i] * acc[i]);
        }
    }
}

// ---------------- sparse aggregation (bf16 H' gathers, weight-free) ----------
// out[n] = b + dinv[n] * ( h'[n] + sum_e h'[ssrc[e]] );  wave/node, uint(2xbf16)/lane.

__device__ __forceinline__ float gelu_f(float x) {
    return 0.5f * x * (1.0f + erff(x * 0.70710678118654752f));
}

__global__ __launch_bounds__(256) void agg_k(const unsigned short* __restrict__ Hb,
                                             const int* __restrict__ rp,
                                             const unsigned short* __restrict__ ssrc,
                                             const float* __restrict__ dinv,
                                             const float* __restrict__ bias,
                                             float* __restrict__ out, int N, int doGelu) {
    int node = blockIdx.x * 4 + (threadIdx.x >> 6);
    int lane = threadIdx.x & 63;
    if (node >= N) return;
    const unsigned int* __restrict__ hb = (const unsigned int*)Hb;
    unsigned int sv = hb[(size_t)node * 64 + lane];
    float ax = __uint_as_float(sv << 16);
    float ay = __uint_as_float(sv & 0xFFFF0000u);
    float bx = 0.f, by = 0.f;
    int e = rp[node];
    int e1 = rp[node + 1];
    for (; e + 8 <= e1; e += 8) {
        int s[8];
        unsigned int v[8];
#pragma unroll
        for (int j = 0; j < 8; ++j) s[j] = ssrc[e + j];
#pragma unroll
        for (int j = 0; j < 8; ++j) v[j] = hb[(size_t)s[j] * 64 + lane];
#pragma unroll
        for (int j = 0; j < 8; ++j) {
            float fx = __uint_as_float(v[j] << 16);
            float fy = __uint_as_float(v[j] & 0xFFFF0000u);
            if (j & 1) { bx += fx; by += fy; }
            else       { ax += fx; ay += fy; }
        }
    }
    for (; e < e1; ++e) {
        int s = ssrc[e];
        unsigned int v = hb[(size_t)s * 64 + lane];
        ax += __uint_as_float(v << 16);
        ay += __uint_as_float(v & 0xFFFF0000u);
    }
    ax += bx; ay += by;
    float dn = dinv[node];
    float2 bv = ((const float2*)bias)[lane];
    ax = dn * ax + bv.x;
    ay = dn * ay + bv.y;
    if (doGelu) { ax = gelu_f(ax); ay = gelu_f(ay); }
    ((float2*)out)[(size_t)node * 64 + lane] = make_float2(ax, ay);
}

// ---------------- launch ----------------

extern "C" void kernel_launch(void* const* d_in, const int* in_sizes, int n_in,
                              void* d_out, int out_size, void* d_ws, size_t ws_size,
                              hipStream_t stream) {
    const float* X  = (const float*)d_in[0];
    const int*   EI = (const int*)d_in[1];
    const float* Wp = (const float*)d_in[2];
    const float* bp = (const float*)d_in[3];
    float* OUT = (float*)d_out;

    int N = in_sizes[0] / D;
    int E = in_sizes[1] / 2;
    int L = in_sizes[3] / D;
    const int* src = EI;
    const int* dst = EI + E;

    char* w = (char*)d_ws;
    auto alloc = [&](size_t bytes) {
        char* p = w;
        w += (bytes + 255) & ~(size_t)255;
        return p;
    };
    unsigned short* HB = (unsigned short*)alloc((size_t)N * D * sizeof(unsigned short)); // 12.8 MB
    float* XB   = (float*)alloc((size_t)N * D * sizeof(float));   // 25.6 MB
    float* DINV = (float*)alloc((size_t)N * sizeof(float));
    int*   RP   = (int*)alloc((size_t)(N + 1) * sizeof(int));
    int*   CNT  = (int*)alloc((size_t)N * sizeof(int));
    int*   BSUM = (int*)alloc(4096 * sizeof(int));
    int*   RANK = (int*)alloc((size_t)E * sizeof(int));
    unsigned short* SSRC = (unsigned short*)alloc((size_t)E * sizeof(unsigned short));
    short* BFH  = (short*)alloc((size_t)L * D * D * sizeof(short));
    short* BFL  = (short*)alloc((size_t)L * D * D * sizeof(short));
    (void)ws_size; (void)n_in; (void)out_size;

    hipMemsetAsync(CNT, 0, (size_t)N * sizeof(int), stream);

    int eb = (E + 255) / 256;
    rank_k<<<eb, 256, 0, stream>>>(dst, E, CNT, RANK);
    int nb = (N + 1023) / 1024;
    scan_a<<<nb, 1024, 0, stream>>>(CNT, N, RP, BSUM);
    scan_b<<<1, 1024, 0, stream>>>(BSUM, nb);
    scan_c<<<(N + 255) / 256, 256, 0, stream>>>(CNT, RP, BSUM, DINV, N, E);
    fill_k<<<eb, 256, 0, stream>>>(src, dst, RANK, RP, E, SSRC);

    int wtot = L * D * D;
    wsplit_k<<<(wtot + 255) / 256, 256, 0, stream>>>(Wp, BFH, BFL, wtot);

    int gb = (N + 63) / 64;
    int ab = (N + 3) / 4;
    for (int l = 0; l < L; ++l) {
        const float* xin = (l == 0) ? X : XB;
        gemm_k<<<gb, 256, 0, stream>>>(xin, BFH + (size_t)l * D * D, BFL + (size_t)l * D * D,
                                       DINV, HB, N);
        float* o = (l == L - 1) ? OUT : XB;
        agg_k<<<ab, 256, 0, stream>>>(HB, RP, SSRC, DINV, bp + (size_t)l * D, o, N,
                                      (l == L - 1) ? 1 : 0);
    }
}

// Round 5
// 233.160 us; speedup vs baseline: 1.9497x; 1.0151x over previous
//
#include <hip/hip_runtime.h>
#include <math.h>

#define D 128

typedef __attribute__((ext_vector_type(8))) short short8v;
typedef __attribute__((ext_vector_type(4))) float f32x4;

__device__ __forceinline__ unsigned short f2bf(float x) {
    unsigned int u = __float_as_uint(x);
    unsigned int r = (u + 0x7FFFu + ((u >> 16) & 1u)) >> 16;
    return (unsigned short)r;
}
__device__ __forceinline__ float bf2f(unsigned short b) {
    return __uint_as_float(((unsigned int)b) << 16);
}

// ---------------- CSR build ----------------

// custom zero: ROCm's fillBufferAligned costs ~42us for tiny buffers (launch-
// latency-bound small grid); this is ~3us.
__global__ void zero_k(int* __restrict__ p, int n) {
    int i = blockIdx.x * blockDim.x + threadIdx.x;
    if (i < n) p[i] = 0;
}

// rank_k: per-edge arrival rank among same-dst edges (atomic WITH return —
// this pass already pays the atomic, so capture rank and make fill atomic-free).
__global__ void rank_k(const int* __restrict__ dst, int E,
                       int* __restrict__ cnt, int* __restrict__ rank) {
    int e = blockIdx.x * blockDim.x + threadIdx.x;
    if (e < E) rank[e] = atomicAdd(&cnt[dst[e]], 1);
}

__global__ __launch_bounds__(1024) void scan_a(const int* __restrict__ cnt, int N,
                                               int* __restrict__ part, int* __restrict__ bsum) {
    __shared__ int s[1024];
    int i = blockIdx.x * 1024 + threadIdx.x;
    int v = (i < N) ? cnt[i] : 0;
    s[threadIdx.x] = v;
    __syncthreads();
    for (int off = 1; off < 1024; off <<= 1) {
        int add = (threadIdx.x >= off) ? s[threadIdx.x - off] : 0;
        __syncthreads();
        s[threadIdx.x] += add;
        __syncthreads();
    }
    if (i < N) part[i] = s[threadIdx.x] - v;   // exclusive within chunk
    if (threadIdx.x == 1023) bsum[blockIdx.x] = s[1023];
}

__global__ __launch_bounds__(1024) void scan_b(int* __restrict__ bsum, int nb) {
    __shared__ int s[1024];
    int v = (threadIdx.x < nb) ? bsum[threadIdx.x] : 0;
    s[threadIdx.x] = v;
    __syncthreads();
    for (int off = 1; off < 1024; off <<= 1) {
        int add = (threadIdx.x >= off) ? s[threadIdx.x - off] : 0;
        __syncthreads();
        s[threadIdx.x] += add;
        __syncthreads();
    }
    if (threadIdx.x < nb) bsum[threadIdx.x] = s[threadIdx.x] - v;  // exclusive
}

__global__ void scan_c(const int* __restrict__ cnt, int* __restrict__ part,
                       const int* __restrict__ bsum,
                       float* __restrict__ dinv, int N, int E) {
    int i = blockIdx.x * blockDim.x + threadIdx.x;
    if (i < N) {
        part[i] = part[i] + bsum[i >> 10];       // row_ptr (exclusive scan)
        dinv[i] = rsqrtf((float)(cnt[i] + 1));   // +1 self-loop; always > 0
    }
    if (i == 0) part[N] = E;
}

// atomic-free fill: position = row_ptr[dst] + rank. ushort col index (N < 65536).
__global__ void fill_k(const int* __restrict__ src, const int* __restrict__ dst,
                       const int* __restrict__ rank, const int* __restrict__ rp,
                       int E, unsigned short* __restrict__ ssrc) {
    int e = blockIdx.x * blockDim.x + threadIdx.x;
    if (e < E) {
        int p = rp[dst[e]] + rank[e];
        ssrc[p] = (unsigned short)src[e];
    }
}

// ---------------- W split: frag-ordered hi/lo bf16 ----------------
// BF[l][ks][ct][lane][i] = bf16split(W[l][ks*32 + (lane>>4)*8 + i][ct*16 + (lane&15)])

__global__ void wsplit_k(const float* __restrict__ Wp, short* __restrict__ BFh,
                         short* __restrict__ BFl, int total) {
    int idx = blockIdx.x * blockDim.x + threadIdx.x;
    if (idx >= total) return;
    int i    = idx & 7;
    int lane = (idx >> 3) & 63;
    int ct   = (idx >> 9) & 7;
    int ks   = (idx >> 12) & 3;
    int l    = idx >> 14;
    int k = ks * 32 + (lane >> 4) * 8 + i;
    int n = ct * 16 + (lane & 15);
    float w = Wp[(size_t)l * (D * D) + (size_t)k * D + n];
    unsigned short h = f2bf(w);
    float lo = w - bf2f(h);
    BFh[idx] = (short)h;
    BFl[idx] = (short)f2bf(lo);
}

// ---------------- GEMM: Hb(bf16) = diag(dinv) * (X(f32) @ W), split-bf16 MFMA ----

__global__ __launch_bounds__(256) void gemm_k(const float* __restrict__ X,
                                              const short* __restrict__ BFh,
                                              const short* __restrict__ BFl,
                                              const float* __restrict__ dinv,
                                              unsigned short* __restrict__ Hb, int M) {
    int lane = threadIdx.x & 63;
    int wv = threadIdx.x >> 6;
    int rowBase = blockIdx.x * 64 + wv * 16;
    int arow = rowBase + (lane & 15);
    bool aval = arow < M;
    const float* xr = X + (size_t)arow * D + (lane >> 4) * 8;

    short8v ah[4], al[4];
#pragma unroll
    for (int ks = 0; ks < 4; ++ks) {
        float4 p = make_float4(0.f, 0.f, 0.f, 0.f);
        float4 q = make_float4(0.f, 0.f, 0.f, 0.f);
        if (aval) {
            p = *(const float4*)(xr + ks * 32);
            q = *(const float4*)(xr + ks * 32 + 4);
        }
        float v[8] = {p.x, p.y, p.z, p.w, q.x, q.y, q.z, q.w};
#pragma unroll
        for (int i = 0; i < 8; ++i) {
            unsigned short h = f2bf(v[i]);
            ah[ks][i] = (short)h;
            al[ks][i] = (short)f2bf(v[i] - bf2f(h));
        }
    }

    int rb = rowBase + (lane >> 4) * 4;
    float dsc[4];
#pragma unroll
    for (int i = 0; i < 4; ++i) dsc[i] = (rb + i < M) ? dinv[rb + i] : 0.f;

    const short8v* Bh = (const short8v*)BFh;
    const short8v* Bl = (const short8v*)BFl;
#pragma unroll
    for (int ct = 0; ct < 8; ++ct) {
        short8v bh[4], bl[4];
#pragma unroll
        for (int ks = 0; ks < 4; ++ks) {
            bh[ks] = Bh[(ks * 8 + ct) * 64 + lane];
            bl[ks] = Bl[(ks * 8 + ct) * 64 + lane];
        }
        f32x4 acc = {0.f, 0.f, 0.f, 0.f};
#pragma unroll
        for (int ks = 0; ks < 4; ++ks) {
            acc = __builtin_amdgcn_mfma_f32_16x16x32_bf16(ah[ks], bh[ks], acc, 0, 0, 0);
            acc = __builtin_amdgcn_mfma_f32_16x16x32_bf16(al[ks], bh[ks], acc, 0, 0, 0);
            acc = __builtin_amdgcn_mfma_f32_16x16x32_bf16(ah[ks], bl[ks], acc, 0, 0, 0);
        }
        int c = ct * 16 + (lane & 15);
#pragma unroll
        for (int i = 0; i < 4; ++i) {
            int r = rb + i;
            if (r < M) Hb[(size_t)r * D + c] = f2bf(dsc[i] * acc[i]);
        }
    }
}

// ---------------- sparse aggregation (bf16 H' gathers, weight-free) ----------
// out[n] = b + dinv[n] * ( h'[n] + sum_e h'[ssrc[e]] );  wave/node, uint(2xbf16)/lane.
// 16/8/scalar MLP ladder: up to 16 row-gathers in flight per wave.

__device__ __forceinline__ float gelu_f(float x) {
    return 0.5f * x * (1.0f + erff(x * 0.70710678118654752f));
}

__global__ __launch_bounds__(256) void agg_k(const unsigned short* __restrict__ Hb,
                                             const int* __restrict__ rp,
                                             const unsigned short* __restrict__ ssrc,
                                             const float* __restrict__ dinv,
                                             const float* __restrict__ bias,
                                             float* __restrict__ out, int N, int doGelu) {
    int node = blockIdx.x * 4 + (threadIdx.x >> 6);
    int lane = threadIdx.x & 63;
    if (node >= N) return;
    const unsigned int* __restrict__ hb = (const unsigned int*)Hb;
    unsigned int sv = hb[(size_t)node * 64 + lane];
    float ax = __uint_as_float(sv << 16);
    float ay = __uint_as_float(sv & 0xFFFF0000u);
    float bx = 0.f, by = 0.f;
    int e = rp[node];
    int e1 = rp[node + 1];
    for (; e + 16 <= e1; e += 16) {
        int s[16];
        unsigned int v[16];
#pragma unroll
        for (int j = 0; j < 16; ++j) s[j] = ssrc[e + j];
#pragma unroll
        for (int j = 0; j < 16; ++j) v[j] = hb[(size_t)s[j] * 64 + lane];
#pragma unroll
        for (int j = 0; j < 16; ++j) {
            float fx = __uint_as_float(v[j] << 16);
            float fy = __uint_as_float(v[j] & 0xFFFF0000u);
            if (j & 1) { bx += fx; by += fy; }
            else       { ax += fx; ay += fy; }
        }
    }
    for (; e + 8 <= e1; e += 8) {
        int s[8];
        unsigned int v[8];
#pragma unroll
        for (int j = 0; j < 8; ++j) s[j] = ssrc[e + j];
#pragma unroll
        for (int j = 0; j < 8; ++j) v[j] = hb[(size_t)s[j] * 64 + lane];
#pragma unroll
        for (int j = 0; j < 8; ++j) {
            float fx = __uint_as_float(v[j] << 16);
            float fy = __uint_as_float(v[j] & 0xFFFF0000u);
            if (j & 1) { bx += fx; by += fy; }
            else       { ax += fx; ay += fy; }
        }
    }
    for (; e < e1; ++e) {
        int s = ssrc[e];
        unsigned int v = hb[(size_t)s * 64 + lane];
        ax += __uint_as_float(v << 16);
        ay += __uint_as_float(v & 0xFFFF0000u);
    }
    ax += bx; ay += by;
    float dn = dinv[node];
    float2 bv = ((const float2*)bias)[lane];
    ax = dn * ax + bv.x;
    ay = dn * ay + bv.y;
    if (doGelu) { ax = gelu_f(ax); ay = gelu_f(ay); }
    ((float2*)out)[(size_t)node * 64 + lane] = make_float2(ax, ay);
}

// ---------------- launch ----------------

extern "C" void kernel_launch(void* const* d_in, const int* in_sizes, int n_in,
                              void* d_out, int out_size, void* d_ws, size_t ws_size,
                              hipStream_t stream) {
    const float* X  = (const float*)d_in[0];
    const int*   EI = (const int*)d_in[1];
    const float* Wp = (const float*)d_in[2];
    const float* bp = (const float*)d_in[3];
    float* OUT = (float*)d_out;

    int N = in_sizes[0] / D;
    int E = in_sizes[1] / 2;
    int L = in_sizes[3] / D;
    const int* src = EI;
    const int* dst = EI + E;

    char* w = (char*)d_ws;
    auto alloc = [&](size_t bytes) {
        char* p = w;
        w += (bytes + 255) & ~(size_t)255;
        return p;
    };
    unsigned short* HB = (unsigned short*)alloc((size_t)N * D * sizeof(unsigned short)); // 12.8 MB
    float* XB   = (float*)alloc((size_t)N * D * sizeof(float));   // 25.6 MB
    float* DINV = (float*)alloc((size_t)N * sizeof(float));
    int*   RP   = (int*)alloc((size_t)(N + 1) * sizeof(int));
    int*   CNT  = (int*)alloc((size_t)N * sizeof(int));
    int*   BSUM = (int*)alloc(4096 * sizeof(int));
    int*   RANK = (int*)alloc((size_t)E * sizeof(int));
    unsigned short* SSRC = (unsigned short*)alloc((size_t)E * sizeof(unsigned short));
    short* BFH  = (short*)alloc((size_t)L * D * D * sizeof(short));
    short* BFL  = (short*)alloc((size_t)L * D * D * sizeof(short));
    (void)ws_size; (void)n_in; (void)out_size;

    zero_k<<<(N + 255) / 256, 256, 0, stream>>>(CNT, N);

    int eb = (E + 255) / 256;
    rank_k<<<eb, 256, 0, stream>>>(dst, E, CNT, RANK);
    int nb = (N + 1023) / 1024;
    scan_a<<<nb, 1024, 0, stream>>>(CNT, N, RP, BSUM);
    scan_b<<<1, 1024, 0, stream>>>(BSUM, nb);
    scan_c<<<(N + 255) / 256, 256, 0, stream>>>(CNT, RP, BSUM, DINV, N, E);
    fill_k<<<eb, 256, 0, stream>>>(src, dst, RANK, RP, E, SSRC);

    int wtot = L * D * D;
    wsplit_k<<<(wtot + 255) / 256, 256, 0, stream>>>(Wp, BFH, BFL, wtot);

    int gb = (N + 63) / 64;
    int ab = (N + 3) / 4;
    for (int l = 0; l < L; ++l) {
        const float* xin = (l == 0) ? X : XB;
        gemm_k<<<gb, 256, 0, stream>>>(xin, BFH + (size_t)l * D * D, BFL + (size_t)l * D * D,
                                       DINV, HB, N);
        float* o = (l == L - 1) ? OUT : XB;
        agg_k<<<ab, 256, 0, stream>>>(HB, RP, SSRC, DINV, bp + (size_t)l * D, o, N,
                                      (l == L - 1) ? 1 : 0);
    }
}

// Round 6
// 216.393 us; speedup vs baseline: 2.1008x; 1.0775x over previous
//
#include <hip/hip_runtime.h>
#include <math.h>

#define D 128

typedef __attribute__((ext_vector_type(8))) short short8v;
typedef __attribute__((ext_vector_type(4))) float f32x4;

__device__ __forceinline__ unsigned short f2bf(float x) {
    unsigned int u = __float_as_uint(x);
    unsigned int r = (u + 0x7FFFu + ((u >> 16) & 1u)) >> 16;
    return (unsigned short)r;
}
__device__ __forceinline__ float bf2f(unsigned short b) {
    return __uint_as_float(((unsigned int)b) << 16);
}

// ---------------- CSR build ----------------

// zero CNT + write the 16 SSRC sentinel entries (node 0) used by the masked
// agg batches. (Custom kernel: rocclr fillBuffer is launch-latency-heavy.)
__global__ void zero_k(int* __restrict__ cnt, int n, unsigned short* __restrict__ stail) {
    int i = blockIdx.x * blockDim.x + threadIdx.x;
    if (i < n) cnt[i] = 0;
    if (i < 16) stail[i] = 0;
}

// rank_k: per-edge arrival rank among same-dst edges (atomic WITH return —
// this pass already pays the atomic, so capture rank and make fill atomic-free).
__global__ void rank_k(const int* __restrict__ dst, int E,
                       int* __restrict__ cnt, unsigned short* __restrict__ rank) {
    int e = blockIdx.x * blockDim.x + threadIdx.x;
    if (e < E) rank[e] = (unsigned short)atomicAdd(&cnt[dst[e]], 1);
}

__global__ __launch_bounds__(1024) void scan_a(const int* __restrict__ cnt, int N,
                                               int* __restrict__ part, int* __restrict__ bsum) {
    __shared__ int s[1024];
    int i = blockIdx.x * 1024 + threadIdx.x;
    int v = (i < N) ? cnt[i] : 0;
    s[threadIdx.x] = v;
    __syncthreads();
    for (int off = 1; off < 1024; off <<= 1) {
        int add = (threadIdx.x >= off) ? s[threadIdx.x - off] : 0;
        __syncthreads();
        s[threadIdx.x] += add;
        __syncthreads();
    }
    if (i < N) part[i] = s[threadIdx.x] - v;   // exclusive within chunk
    if (threadIdx.x == 1023) bsum[blockIdx.x] = s[1023];
}

__global__ __launch_bounds__(1024) void scan_b(int* __restrict__ bsum, int nb) {
    __shared__ int s[1024];
    int v = (threadIdx.x < nb) ? bsum[threadIdx.x] : 0;
    s[threadIdx.x] = v;
    __syncthreads();
    for (int off = 1; off < 1024; off <<= 1) {
        int add = (threadIdx.x >= off) ? s[threadIdx.x - off] : 0;
        __syncthreads();
        s[threadIdx.x] += add;
        __syncthreads();
    }
    if (threadIdx.x < nb) bsum[threadIdx.x] = s[threadIdx.x] - v;  // exclusive
}

__global__ void scan_c(const int* __restrict__ cnt, int* __restrict__ part,
                       const int* __restrict__ bsum,
                       float* __restrict__ dinv, int N, int E) {
    int i = blockIdx.x * blockDim.x + threadIdx.x;
    if (i < N) {
        part[i] = part[i] + bsum[i >> 10];       // row_ptr (exclusive scan)
        dinv[i] = rsqrtf((float)(cnt[i] + 1));   // +1 self-loop; always > 0
    }
    if (i == 0) part[N] = E;
}

// atomic-free fill: position = row_ptr[dst] + rank. ushort col index (N < 65536).
__global__ void fill_k(const int* __restrict__ src, const int* __restrict__ dst,
                       const unsigned short* __restrict__ rank, const int* __restrict__ rp,
                       int E, unsigned short* __restrict__ ssrc) {
    int e = blockIdx.x * blockDim.x + threadIdx.x;
    if (e < E) {
        int p = rp[dst[e]] + (int)rank[e];
        ssrc[p] = (unsigned short)src[e];
    }
}

// ---------------- W split: frag-ordered hi/lo bf16 ----------------
// BF[l][ks][ct][lane][i] = bf16split(W[l][ks*32 + (lane>>4)*8 + i][ct*16 + (lane&15)])

__global__ void wsplit_k(const float* __restrict__ Wp, short* __restrict__ BFh,
                         short* __restrict__ BFl, int total) {
    int idx = blockIdx.x * blockDim.x + threadIdx.x;
    if (idx >= total) return;
    int i    = idx & 7;
    int lane = (idx >> 3) & 63;
    int ct   = (idx >> 9) & 7;
    int ks   = (idx >> 12) & 3;
    int l    = idx >> 14;
    int k = ks * 32 + (lane >> 4) * 8 + i;
    int n = ct * 16 + (lane & 15);
    float w = Wp[(size_t)l * (D * D) + (size_t)k * D + n];
    unsigned short h = f2bf(w);
    float lo = w - bf2f(h);
    BFh[idx] = (short)h;
    BFl[idx] = (short)f2bf(lo);
}

// ---------------- GEMM: Hb(bf16) = diag(dinv) * (X(f32) @ W), split-bf16 MFMA ----

__global__ __launch_bounds__(256) void gemm_k(const float* __restrict__ X,
                                              const short* __restrict__ BFh,
                                              const short* __restrict__ BFl,
                                              const float* __restrict__ dinv,
                                              unsigned short* __restrict__ Hb, int M) {
    int lane = threadIdx.x & 63;
    int wv = threadIdx.x >> 6;
    int rowBase = blockIdx.x * 64 + wv * 16;
    int arow = rowBase + (lane & 15);
    bool aval = arow < M;
    const float* xr = X + (size_t)arow * D + (lane >> 4) * 8;

    short8v ah[4], al[4];
#pragma unroll
    for (int ks = 0; ks < 4; ++ks) {
        float4 p = make_float4(0.f, 0.f, 0.f, 0.f);
        float4 q = make_float4(0.f, 0.f, 0.f, 0.f);
        if (aval) {
            p = *(const float4*)(xr + ks * 32);
            q = *(const float4*)(xr + ks * 32 + 4);
        }
        float v[8] = {p.x, p.y, p.z, p.w, q.x, q.y, q.z, q.w};
#pragma unroll
        for (int i = 0; i < 8; ++i) {
            unsigned short h = f2bf(v[i]);
            ah[ks][i] = (short)h;
            al[ks][i] = (short)f2bf(v[i] - bf2f(h));
        }
    }

    int rb = rowBase + (lane >> 4) * 4;
    float dsc[4];
#pragma unroll
    for (int i = 0; i < 4; ++i) dsc[i] = (rb + i < M) ? dinv[rb + i] : 0.f;

    const short8v* Bh = (const short8v*)BFh;
    const short8v* Bl = (const short8v*)BFl;
#pragma unroll
    for (int ct = 0; ct < 8; ++ct) {
        short8v bh[4], bl[4];
#pragma unroll
        for (int ks = 0; ks < 4; ++ks) {
            bh[ks] = Bh[(ks * 8 + ct) * 64 + lane];
            bl[ks] = Bl[(ks * 8 + ct) * 64 + lane];
        }
        f32x4 acc = {0.f, 0.f, 0.f, 0.f};
#pragma unroll
        for (int ks = 0; ks < 4; ++ks) {
            acc = __builtin_amdgcn_mfma_f32_16x16x32_bf16(ah[ks], bh[ks], acc, 0, 0, 0);
            acc = __builtin_amdgcn_mfma_f32_16x16x32_bf16(al[ks], bh[ks], acc, 0, 0, 0);
            acc = __builtin_amdgcn_mfma_f32_16x16x32_bf16(ah[ks], bl[ks], acc, 0, 0, 0);
        }
        int c = ct * 16 + (lane & 15);
#pragma unroll
        for (int i = 0; i < 4; ++i) {
            int r = rb + i;
            if (r < M) Hb[(size_t)r * D + c] = f2bf(dsc[i] * acc[i]);
        }
    }
}

// ---------------- sparse aggregation (bf16 H' gathers, weight-free) ----------
// out[n] = b + dinv[n] * ( h'[n] + sum_e h'[ssrc[e]] );  wave/node, uint(2xbf16)/lane.
// Fully-masked 16-batches: no scalar tail, every node = ceil(deg/16) parallel
// gather rounds. Masked lanes gather SSRC sentinel (node 0, L1-hot), zeroed by
// wave-uniform select.

__device__ __forceinline__ float gelu_f(float x) {
    return 0.5f * x * (1.0f + erff(x * 0.70710678118654752f));
}

__global__ __launch_bounds__(256) void agg_k(const unsigned short* __restrict__ Hb,
                                             const int* __restrict__ rp,
                                             const unsigned short* __restrict__ ssrc,
                                             const float* __restrict__ dinv,
                                             const float* __restrict__ bias,
                                             float* __restrict__ out, int N, int doGelu) {
    int node = blockIdx.x * 4 + (threadIdx.x >> 6);
    int lane = threadIdx.x & 63;
    if (node >= N) return;
    const unsigned int* __restrict__ hb = (const unsigned int*)Hb;
    unsigned int sv = hb[(size_t)node * 64 + lane];
    float ax = __uint_as_float(sv << 16);
    float ay = __uint_as_float(sv & 0xFFFF0000u);
    float bx = 0.f, by = 0.f;
    int e0 = rp[node];
    int e1 = rp[node + 1];
    for (int e = e0; e < e1; e += 16) {
        int s[16];
        unsigned int v[16];
#pragma unroll
        for (int j = 0; j < 16; ++j) s[j] = (int)ssrc[e + j];   // tail reads sentinel
#pragma unroll
        for (int j = 0; j < 16; ++j) v[j] = hb[(size_t)s[j] * 64 + lane];
#pragma unroll
        for (int j = 0; j < 16; ++j) {
            unsigned int m = (e + j < e1) ? v[j] : 0u;          // wave-uniform select
            float fx = __uint_as_float(m << 16);
            float fy = __uint_as_float(m & 0xFFFF0000u);
            if (j & 1) { bx += fx; by += fy; }
            else       { ax += fx; ay += fy; }
        }
    }
    ax += bx; ay += by;
    float dn = dinv[node];
    float2 bv = ((const float2*)bias)[lane];
    ax = dn * ax + bv.x;
    ay = dn * ay + bv.y;
    if (doGelu) { ax = gelu_f(ax); ay = gelu_f(ay); }
    ((float2*)out)[(size_t)node * 64 + lane] = make_float2(ax, ay);
}

// ---------------- launch ----------------

extern "C" void kernel_launch(void* const* d_in, const int* in_sizes, int n_in,
                              void* d_out, int out_size, void* d_ws, size_t ws_size,
                              hipStream_t stream) {
    const float* X  = (const float*)d_in[0];
    const int*   EI = (const int*)d_in[1];
    const float* Wp = (const float*)d_in[2];
    const float* bp = (const float*)d_in[3];
    float* OUT = (float*)d_out;

    int N = in_sizes[0] / D;
    int E = in_sizes[1] / 2;
    int L = in_sizes[3] / D;
    const int* src = EI;
    const int* dst = EI + E;

    char* w = (char*)d_ws;
    auto alloc = [&](size_t bytes) {
        char* p = w;
        w += (bytes + 255) & ~(size_t)255;
        return p;
    };
    unsigned short* HB = (unsigned short*)alloc((size_t)N * D * sizeof(unsigned short)); // 12.8 MB
    float* XB   = (float*)alloc((size_t)N * D * sizeof(float));   // 25.6 MB
    float* DINV = (float*)alloc((size_t)N * sizeof(float));
    int*   RP   = (int*)alloc((size_t)(N + 1) * sizeof(int));
    int*   CNT  = (int*)alloc((size_t)N * sizeof(int));
    int*   BSUM = (int*)alloc(4096 * sizeof(int));
    unsigned short* RANK = (unsigned short*)alloc((size_t)E * sizeof(unsigned short));
    unsigned short* SSRC = (unsigned short*)alloc(((size_t)E + 16) * sizeof(unsigned short));
    short* BFH  = (short*)alloc((size_t)L * D * D * sizeof(short));
    short* BFL  = (short*)alloc((size_t)L * D * D * sizeof(short));
    (void)ws_size; (void)n_in; (void)out_size;

    zero_k<<<(N + 255) / 256, 256, 0, stream>>>(CNT, N, SSRC + E);

    int eb = (E + 255) / 256;
    rank_k<<<eb, 256, 0, stream>>>(dst, E, CNT, RANK);
    int nb = (N + 1023) / 1024;
    scan_a<<<nb, 1024, 0, stream>>>(CNT, N, RP, BSUM);
    scan_b<<<1, 1024, 0, stream>>>(BSUM, nb);
    scan_c<<<(N + 255) / 256, 256, 0, stream>>>(CNT, RP, BSUM, DINV, N, E);
    fill_k<<<eb, 256, 0, stream>>>(src, dst, RANK, RP, E, SSRC);

    int wtot = L * D * D;
    wsplit_k<<<(wtot + 255) / 256, 256, 0, stream>>>(Wp, BFH, BFL, wtot);

    int gb = (N + 63) / 64;
    int ab = (N + 3) / 4;
    for (int l = 0; l < L; ++l) {
        const float* xin = (l == 0) ? X : XB;
        gemm_k<<<gb, 256, 0, stream>>>(xin, BFH + (size_t)l * D * D, BFL + (size_t)l * D * D,
                                       DINV, HB, N);
        float* o = (l == L - 1) ? OUT : XB;
        agg_k<<<ab, 256, 0, stream>>>(HB, RP, SSRC, DINV, bp + (size_t)l * D, o, N,
                                      (l == L - 1) ? 1 : 0);
    }
}

// Round 7
// 212.057 us; speedup vs baseline: 2.1437x; 1.0204x over previous
//
#include <hip/hip_runtime.h>
#include <math.h>

#define D 128

typedef __attribute__((ext_vector_type(8))) short short8v;
typedef __attribute__((ext_vector_type(4))) float f32x4;

__device__ __forceinline__ unsigned short f2bf(float x) {
    unsigned int u = __float_as_uint(x);
    unsigned int r = (u + 0x7FFFu + ((u >> 16) & 1u)) >> 16;
    return (unsigned short)r;
}
__device__ __forceinline__ float bf2f(unsigned short b) {
    return __uint_as_float(((unsigned int)b) << 16);
}

// ---------------- CSR build ----------------

// zero CNT (custom kernel: rocclr fillBuffer is launch-latency-heavy for tiny buffers)
__global__ void zero_k(int* __restrict__ cnt, int n) {
    int i = blockIdx.x * blockDim.x + threadIdx.x;
    if (i < n) cnt[i] = 0;
}

// rank_k: per-edge arrival rank among same-dst edges (atomic WITH return —
// this pass already pays the atomic, so capture rank and make fill atomic-free).
__global__ void rank_k(const int* __restrict__ dst, int E,
                       int* __restrict__ cnt, unsigned short* __restrict__ rank) {
    int e = blockIdx.x * blockDim.x + threadIdx.x;
    if (e < E) rank[e] = (unsigned short)atomicAdd(&cnt[dst[e]], 1);
}

__global__ __launch_bounds__(1024) void scan_a(const int* __restrict__ cnt, int N,
                                               int* __restrict__ part, int* __restrict__ bsum) {
    __shared__ int s[1024];
    int i = blockIdx.x * 1024 + threadIdx.x;
    int v = (i < N) ? cnt[i] : 0;
    s[threadIdx.x] = v;
    __syncthreads();
    for (int off = 1; off < 1024; off <<= 1) {
        int add = (threadIdx.x >= off) ? s[threadIdx.x - off] : 0;
        __syncthreads();
        s[threadIdx.x] += add;
        __syncthreads();
    }
    if (i < N) part[i] = s[threadIdx.x] - v;   // exclusive within chunk
    if (threadIdx.x == 1023) bsum[blockIdx.x] = s[1023];
}

__global__ __launch_bounds__(1024) void scan_b(int* __restrict__ bsum, int nb) {
    __shared__ int s[1024];
    int v = (threadIdx.x < nb) ? bsum[threadIdx.x] : 0;
    s[threadIdx.x] = v;
    __syncthreads();
    for (int off = 1; off < 1024; off <<= 1) {
        int add = (threadIdx.x >= off) ? s[threadIdx.x - off] : 0;
        __syncthreads();
        s[threadIdx.x] += add;
        __syncthreads();
    }
    if (threadIdx.x < nb) bsum[threadIdx.x] = s[threadIdx.x] - v;  // exclusive
}

__global__ void scan_c(const int* __restrict__ cnt, int* __restrict__ part,
                       const int* __restrict__ bsum,
                       float* __restrict__ dinv, int N, int E) {
    int i = blockIdx.x * blockDim.x + threadIdx.x;
    if (i < N) {
        part[i] = part[i] + bsum[i >> 10];       // row_ptr (exclusive scan)
        dinv[i] = rsqrtf((float)(cnt[i] + 1));   // +1 self-loop; always > 0
    }
    if (i == 0) part[N] = E;
}

// atomic-free fill: position = row_ptr[dst] + rank. ushort col index (N < 65536).
__global__ void fill_k(const int* __restrict__ src, const int* __restrict__ dst,
                       const unsigned short* __restrict__ rank, const int* __restrict__ rp,
                       int E, unsigned short* __restrict__ ssrc) {
    int e = blockIdx.x * blockDim.x + threadIdx.x;
    if (e < E) {
        int p = rp[dst[e]] + (int)rank[e];
        ssrc[p] = (unsigned short)src[e];
    }
}

// ---------------- W split: frag-ordered hi/lo bf16 ----------------
// BF[l][ks][ct][lane][i] = bf16split(W[l][ks*32 + (lane>>4)*8 + i][ct*16 + (lane&15)])

__global__ void wsplit_k(const float* __restrict__ Wp, short* __restrict__ BFh,
                         short* __restrict__ BFl, int total) {
    int idx = blockIdx.x * blockDim.x + threadIdx.x;
    if (idx >= total) return;
    int i    = idx & 7;
    int lane = (idx >> 3) & 63;
    int ct   = (idx >> 9) & 7;
    int ks   = (idx >> 12) & 3;
    int l    = idx >> 14;
    int k = ks * 32 + (lane >> 4) * 8 + i;
    int n = ct * 16 + (lane & 15);
    float w = Wp[(size_t)l * (D * D) + (size_t)k * D + n];
    unsigned short h = f2bf(w);
    float lo = w - bf2f(h);
    BFh[idx] = (short)h;
    BFl[idx] = (short)f2bf(lo);
}

// ---------------- GEMM: Hb(bf16) = diag(dinv) * (X(f32) @ W), split-bf16 MFMA ----

__global__ __launch_bounds__(256) void gemm_k(const float* __restrict__ X,
                                              const short* __restrict__ BFh,
                                              const short* __restrict__ BFl,
                                              const float* __restrict__ dinv,
                                              unsigned short* __restrict__ Hb, int M) {
    int lane = threadIdx.x & 63;
    int wv = threadIdx.x >> 6;
    int rowBase = blockIdx.x * 64 + wv * 16;
    int arow = rowBase + (lane & 15);
    bool aval = arow < M;
    const float* xr = X + (size_t)arow * D + (lane >> 4) * 8;

    short8v ah[4], al[4];
#pragma unroll
    for (int ks = 0; ks < 4; ++ks) {
        float4 p = make_float4(0.f, 0.f, 0.f, 0.f);
        float4 q = make_float4(0.f, 0.f, 0.f, 0.f);
        if (aval) {
            p = *(const float4*)(xr + ks * 32);
            q = *(const float4*)(xr + ks * 32 + 4);
        }
        float v[8] = {p.x, p.y, p.z, p.w, q.x, q.y, q.z, q.w};
#pragma unroll
        for (int i = 0; i < 8; ++i) {
            unsigned short h = f2bf(v[i]);
            ah[ks][i] = (short)h;
            al[ks][i] = (short)f2bf(v[i] - bf2f(h));
        }
    }

    int rb = rowBase + (lane >> 4) * 4;
    float dsc[4];
#pragma unroll
    for (int i = 0; i < 4; ++i) dsc[i] = (rb + i < M) ? dinv[rb + i] : 0.f;

    const short8v* Bh = (const short8v*)BFh;
    const short8v* Bl = (const short8v*)BFl;
#pragma unroll
    for (int ct = 0; ct < 8; ++ct) {
        short8v bh[4], bl[4];
#pragma unroll
        for (int ks = 0; ks < 4; ++ks) {
            bh[ks] = Bh[(ks * 8 + ct) * 64 + lane];
            bl[ks] = Bl[(ks * 8 + ct) * 64 + lane];
        }
        f32x4 acc = {0.f, 0.f, 0.f, 0.f};
#pragma unroll
        for (int ks = 0; ks < 4; ++ks) {
            acc = __builtin_amdgcn_mfma_f32_16x16x32_bf16(ah[ks], bh[ks], acc, 0, 0, 0);
            acc = __builtin_amdgcn_mfma_f32_16x16x32_bf16(al[ks], bh[ks], acc, 0, 0, 0);
            acc = __builtin_amdgcn_mfma_f32_16x16x32_bf16(ah[ks], bl[ks], acc, 0, 0, 0);
        }
        int c = ct * 16 + (lane & 15);
#pragma unroll
        for (int i = 0; i < 4; ++i) {
            int r = rb + i;
            if (r < M) Hb[(size_t)r * D + c] = f2bf(dsc[i] * acc[i]);
        }
    }
}

// ---------------- sparse aggregation (bf16 H' gathers, weight-free) ----------
// out[n] = b + dinv[n] * ( h'[n] + sum_e h'[ssrc[e]] );  wave/node, uint(2xbf16)/lane.
// v3: ONE coalesced index load per 64 edges (ssrc[base+lane]) + __shfl
// broadcast, then masked 16-gather chunks — removes the per-round broadcast
// index loads and their serial idx->gather latency chain.

__device__ __forceinline__ float gelu_f(float x) {
    return 0.5f * x * (1.0f + erff(x * 0.70710678118654752f));
}

__global__ __launch_bounds__(256) void agg_k(const unsigned short* __restrict__ Hb,
                                             const int* __restrict__ rp,
                                             const unsigned short* __restrict__ ssrc,
                                             const float* __restrict__ dinv,
                                             const float* __restrict__ bias,
                                             float* __restrict__ out, int N, int doGelu) {
    int node = blockIdx.x * 4 + (threadIdx.x >> 6);
    int lane = threadIdx.x & 63;
    if (node >= N) return;
    const unsigned int* __restrict__ hb = (const unsigned int*)Hb;
    unsigned int sv = hb[(size_t)node * 64 + lane];
    float ax = __uint_as_float(sv << 16);
    float ay = __uint_as_float(sv & 0xFFFF0000u);
    float bx = 0.f, by = 0.f;
    int e0 = rp[node];
    int e1 = rp[node + 1];
    for (int base = e0; base < e1; base += 64) {
        int idxv = 0;                                    // masked lanes -> row 0 (L1-hot)
        if (base + lane < e1) idxv = (int)ssrc[base + lane];  // 1 coalesced load / 64 edges
        int cnt = e1 - base; if (cnt > 64) cnt = 64;
        for (int c = 0; c < cnt; c += 16) {
            int s[16];
            unsigned int v[16];
#pragma unroll
            for (int j = 0; j < 16; ++j) s[j] = __shfl(idxv, c + j);
#pragma unroll
            for (int j = 0; j < 16; ++j) v[j] = hb[(size_t)s[j] * 64 + lane];
#pragma unroll
            for (int j = 0; j < 16; ++j) {
                unsigned int m = (c + j < cnt) ? v[j] : 0u;   // wave-uniform select
                float fx = __uint_as_float(m << 16);
                float fy = __uint_as_float(m & 0xFFFF0000u);
                if (j & 1) { bx += fx; by += fy; }
                else       { ax += fx; ay += fy; }
            }
        }
    }
    ax += bx; ay += by;
    float dn = dinv[node];
    float2 bv = ((const float2*)bias)[lane];
    ax = dn * ax + bv.x;
    ay = dn * ay + bv.y;
    if (doGelu) { ax = gelu_f(ax); ay = gelu_f(ay); }
    ((float2*)out)[(size_t)node * 64 + lane] = make_float2(ax, ay);
}

// ---------------- launch ----------------

extern "C" void kernel_launch(void* const* d_in, const int* in_sizes, int n_in,
                              void* d_out, int out_size, void* d_ws, size_t ws_size,
                              hipStream_t stream) {
    const float* X  = (const float*)d_in[0];
    const int*   EI = (const int*)d_in[1];
    const float* Wp = (const float*)d_in[2];
    const float* bp = (const float*)d_in[3];
    float* OUT = (float*)d_out;

    int N = in_sizes[0] / D;
    int E = in_sizes[1] / 2;
    int L = in_sizes[3] / D;
    const int* src = EI;
    const int* dst = EI + E;

    char* w = (char*)d_ws;
    auto alloc = [&](size_t bytes) {
        char* p = w;
        w += (bytes + 255) & ~(size_t)255;
        return p;
    };
    unsigned short* HB = (unsigned short*)alloc((size_t)N * D * sizeof(unsigned short)); // 12.8 MB
    float* XB   = (float*)alloc((size_t)N * D * sizeof(float));   // 25.6 MB
    float* DINV = (float*)alloc((size_t)N * sizeof(float));
    int*   RP   = (int*)alloc((size_t)(N + 1) * sizeof(int));
    int*   CNT  = (int*)alloc((size_t)N * sizeof(int));
    int*   BSUM = (int*)alloc(4096 * sizeof(int));
    unsigned short* RANK = (unsigned short*)alloc((size_t)E * sizeof(unsigned short));
    unsigned short* SSRC = (unsigned short*)alloc(((size_t)E + 64) * sizeof(unsigned short));
    short* BFH  = (short*)alloc((size_t)L * D * D * sizeof(short));
    short* BFL  = (short*)alloc((size_t)L * D * D * sizeof(short));
    (void)ws_size; (void)n_in; (void)out_size;

    zero_k<<<(N + 255) / 256, 256, 0, stream>>>(CNT, N);

    int eb = (E + 255) / 256;
    rank_k<<<eb, 256, 0, stream>>>(dst, E, CNT, RANK);
    int nb = (N + 1023) / 1024;
    scan_a<<<nb, 1024, 0, stream>>>(CNT, N, RP, BSUM);
    scan_b<<<1, 1024, 0, stream>>>(BSUM, nb);
    scan_c<<<(N + 255) / 256, 256, 0, stream>>>(CNT, RP, BSUM, DINV, N, E);
    fill_k<<<eb, 256, 0, stream>>>(src, dst, RANK, RP, E, SSRC);

    int wtot = L * D * D;
    wsplit_k<<<(wtot + 255) / 256, 256, 0, stream>>>(Wp, BFH, BFL, wtot);

    int gb = (N + 63) / 64;
    int ab = (N + 3) / 4;
    for (int l = 0; l < L; ++l) {
        const float* xin = (l == 0) ? X : XB;
        gemm_k<<<gb, 256, 0, stream>>>(xin, BFH + (size_t)l * D * D, BFL + (size_t)l * D * D,
                                       DINV, HB, N);
        float* o = (l == L - 1) ? OUT : XB;
        agg_k<<<ab, 256, 0, stream>>>(HB, RP, SSRC, DINV, bp + (size_t)l * D, o, N,
                                      (l == L - 1) ? 1 : 0);
    }
}

// Round 8
// 210.797 us; speedup vs baseline: 2.1565x; 1.0060x over previous
//
#include <hip/hip_runtime.h>
#include <math.h>

#define D 128

typedef __attribute__((ext_vector_type(8))) short short8v;
typedef __attribute__((ext_vector_type(4))) float f32x4;

__device__ __forceinline__ unsigned short f2bf(float x) {
    unsigned int u = __float_as_uint(x);
    unsigned int r = (u + 0x7FFFu + ((u >> 16) & 1u)) >> 16;
    return (unsigned short)r;
}
__device__ __forceinline__ float bf2f(unsigned short b) {
    return __uint_as_float(((unsigned int)b) << 16);
}

// ---------------- CSR build ----------------

// zero CNT (custom kernel: rocclr fillBuffer is launch-latency-heavy for tiny buffers)
__global__ void zero_k(int* __restrict__ cnt, int n) {
    int i = blockIdx.x * blockDim.x + threadIdx.x;
    if (i < n) cnt[i] = 0;
}

// rank_k: per-edge arrival rank among same-dst edges (atomic WITH return —
// this pass already pays the atomic, so capture rank and make fill atomic-free).
__global__ void rank_k(const int* __restrict__ dst, int E,
                       int* __restrict__ cnt, unsigned short* __restrict__ rank) {
    int e = blockIdx.x * blockDim.x + threadIdx.x;
    if (e < E) rank[e] = (unsigned short)atomicAdd(&cnt[dst[e]], 1);
}

__global__ __launch_bounds__(1024) void scan_a(const int* __restrict__ cnt, int N,
                                               int* __restrict__ part, int* __restrict__ bsum) {
    __shared__ int s[1024];
    int i = blockIdx.x * 1024 + threadIdx.x;
    int v = (i < N) ? cnt[i] : 0;
    s[threadIdx.x] = v;
    __syncthreads();
    for (int off = 1; off < 1024; off <<= 1) {
        int add = (threadIdx.x >= off) ? s[threadIdx.x - off] : 0;
        __syncthreads();
        s[threadIdx.x] += add;
        __syncthreads();
    }
    if (i < N) part[i] = s[threadIdx.x] - v;   // exclusive within chunk
    if (threadIdx.x == 1023) bsum[blockIdx.x] = s[1023];
}

// scan_c with fused block-sum prefix: each 256-thread block covers exactly one
// 1024-chunk (256 | 1024), so first wave reduces bsum[0..chunk) locally —
// scan_b dispatch eliminated. Requires nb <= 64 (N <= 65536).
__global__ __launch_bounds__(256) void scan_c(const int* __restrict__ cnt, int* __restrict__ part,
                                              const int* __restrict__ bsum,
                                              float* __restrict__ dinv, int N, int E) {
    __shared__ int s_pref;
    int chunk = blockIdx.x >> 2;                 // (blockIdx*256)>>10
    if (threadIdx.x < 64) {
        int v = (threadIdx.x < chunk) ? bsum[threadIdx.x] : 0;
#pragma unroll
        for (int off = 1; off < 64; off <<= 1) v += __shfl_xor(v, off);
        if (threadIdx.x == 0) s_pref = v;
    }
    __syncthreads();
    int i = blockIdx.x * blockDim.x + threadIdx.x;
    if (i < N) {
        part[i] = part[i] + s_pref;              // row_ptr (exclusive scan)
        dinv[i] = rsqrtf((float)(cnt[i] + 1));   // +1 self-loop; always > 0
    }
    if (i == 0) part[N] = E;
}

// atomic-free fill: position = row_ptr[dst] + rank. ushort col index (N < 65536).
__global__ void fill_k(const int* __restrict__ src, const int* __restrict__ dst,
                       const unsigned short* __restrict__ rank, const int* __restrict__ rp,
                       int E, unsigned short* __restrict__ ssrc) {
    int e = blockIdx.x * blockDim.x + threadIdx.x;
    if (e < E) {
        int p = rp[dst[e]] + (int)rank[e];
        ssrc[p] = (unsigned short)src[e];
    }
}

// ---------------- W split: frag-ordered hi/lo bf16 ----------------
// BF[l][ks][ct][lane][i] = bf16split(W[l][ks*32 + (lane>>4)*8 + i][ct*16 + (lane&15)])

__global__ void wsplit_k(const float* __restrict__ Wp, short* __restrict__ BFh,
                         short* __restrict__ BFl, int total) {
    int idx = blockIdx.x * blockDim.x + threadIdx.x;
    if (idx >= total) return;
    int i    = idx & 7;
    int lane = (idx >> 3) & 63;
    int ct   = (idx >> 9) & 7;
    int ks   = (idx >> 12) & 3;
    int l    = idx >> 14;
    int k = ks * 32 + (lane >> 4) * 8 + i;
    int n = ct * 16 + (lane & 15);
    float w = Wp[(size_t)l * (D * D) + (size_t)k * D + n];
    unsigned short h = f2bf(w);
    float lo = w - bf2f(h);
    BFh[idx] = (short)h;
    BFl[idx] = (short)f2bf(lo);
}

// ---------------- GEMM: Hb(bf16) = diag(dinv) * (X(f32) @ W), split-bf16 MFMA ----

__global__ __launch_bounds__(256) void gemm_k(const float* __restrict__ X,
                                              const short* __restrict__ BFh,
                                              const short* __restrict__ BFl,
                                              const float* __restrict__ dinv,
                                              unsigned short* __restrict__ Hb, int M) {
    int lane = threadIdx.x & 63;
    int wv = threadIdx.x >> 6;
    int rowBase = blockIdx.x * 64 + wv * 16;
    int arow = rowBase + (lane & 15);
    bool aval = arow < M;
    const float* xr = X + (size_t)arow * D + (lane >> 4) * 8;

    short8v ah[4], al[4];
#pragma unroll
    for (int ks = 0; ks < 4; ++ks) {
        float4 p = make_float4(0.f, 0.f, 0.f, 0.f);
        float4 q = make_float4(0.f, 0.f, 0.f, 0.f);
        if (aval) {
            p = *(const float4*)(xr + ks * 32);
            q = *(const float4*)(xr + ks * 32 + 4);
        }
        float v[8] = {p.x, p.y, p.z, p.w, q.x, q.y, q.z, q.w};
#pragma unroll
        for (int i = 0; i < 8; ++i) {
            unsigned short h = f2bf(v[i]);
            ah[ks][i] = (short)h;
            al[ks][i] = (short)f2bf(v[i] - bf2f(h));
        }
    }

    int rb = rowBase + (lane >> 4) * 4;
    float dsc[4];
#pragma unroll
    for (int i = 0; i < 4; ++i) dsc[i] = (rb + i < M) ? dinv[rb + i] : 0.f;

    const short8v* Bh = (const short8v*)BFh;
    const short8v* Bl = (const short8v*)BFl;
#pragma unroll
    for (int ct = 0; ct < 8; ++ct) {
        short8v bh[4], bl[4];
#pragma unroll
        for (int ks = 0; ks < 4; ++ks) {
            bh[ks] = Bh[(ks * 8 + ct) * 64 + lane];
            bl[ks] = Bl[(ks * 8 + ct) * 64 + lane];
        }
        f32x4 acc = {0.f, 0.f, 0.f, 0.f};
#pragma unroll
        for (int ks = 0; ks < 4; ++ks) {
            acc = __builtin_amdgcn_mfma_f32_16x16x32_bf16(ah[ks], bh[ks], acc, 0, 0, 0);
            acc = __builtin_amdgcn_mfma_f32_16x16x32_bf16(al[ks], bh[ks], acc, 0, 0, 0);
            acc = __builtin_amdgcn_mfma_f32_16x16x32_bf16(ah[ks], bl[ks], acc, 0, 0, 0);
        }
        int c = ct * 16 + (lane & 15);
#pragma unroll
        for (int i = 0; i < 4; ++i) {
            int r = rb + i;
            if (r < M) Hb[(size_t)r * D + c] = f2bf(dsc[i] * acc[i]);
        }
    }
}

// ---------------- sparse aggregation (bf16 H' gathers, weight-free) ----------
// out[n] = b + dinv[n] * ( h'[n] + sum_e h'[ssrc[e]] )
// v4: 4 edge-rows per VMEM instruction. Lanes grouped 16x4: lane = grp*16+sub;
// one uint4 load/lane fetches 16 B of row s[4j+grp] -> 1024 B per instruction
// (4x fewer gather instructions vs 256 B wave-gathers; tests MSHR/instr bound).
// Butterfly shfl_xor(16,32) combines edge groups; lanes 0-15 do the epilogue.

__device__ __forceinline__ float gelu_f(float x) {
    return 0.5f * x * (1.0f + erff(x * 0.70710678118654752f));
}

__global__ __launch_bounds__(256) void agg_k(const unsigned short* __restrict__ Hb,
                                             const int* __restrict__ rp,
                                             const unsigned short* __restrict__ ssrc,
                                             const float* __restrict__ dinv,
                                             const float* __restrict__ bias,
                                             float* __restrict__ out, int N, int doGelu) {
    int node = blockIdx.x * 4 + (threadIdx.x >> 6);
    int lane = threadIdx.x & 63;
    if (node >= N) return;
    const uint4* __restrict__ hb4 = (const uint4*)Hb;   // 16 uint4 per 128-col row
    int grp = lane >> 4;      // which of 4 rows per instruction this lane serves
    int sub = lane & 15;      // 16B sub-block within the row

    float acc[8];
#pragma unroll
    for (int i = 0; i < 8; ++i) acc[i] = 0.f;

    int e0 = rp[node];
    int e1 = rp[node + 1];
    for (int base = e0; base < e1; base += 64) {
        int idxv = 0;                                         // masked -> row 0 (L1-hot)
        if (base + lane < e1) idxv = (int)ssrc[base + lane];  // 1 coalesced load / 64 edges
        int cnt = e1 - base; if (cnt > 64) cnt = 64;
        for (int c = 0; c < cnt; c += 16) {                   // 16 edges per round
            uint4 v[4];
#pragma unroll
            for (int j = 0; j < 4; ++j) {
                int row = __shfl(idxv, c + 4 * j + grp);      // bpermute broadcast
                v[j] = hb4[(size_t)row * 16 + sub];
            }
#pragma unroll
            for (int j = 0; j < 4; ++j) {
                bool ok = (base + c + 4 * j + grp) < e1;
                unsigned int w;
                w = ok ? v[j].x : 0u;
                acc[0] += __uint_as_float(w << 16); acc[1] += __uint_as_float(w & 0xFFFF0000u);
                w = ok ? v[j].y : 0u;
                acc[2] += __uint_as_float(w << 16); acc[3] += __uint_as_float(w & 0xFFFF0000u);
                w = ok ? v[j].z : 0u;
                acc[4] += __uint_as_float(w << 16); acc[5] += __uint_as_float(w & 0xFFFF0000u);
                w = ok ? v[j].w : 0u;
                acc[6] += __uint_as_float(w << 16); acc[7] += __uint_as_float(w & 0xFFFF0000u);
            }
        }
    }
    // combine the 4 edge-groups: butterfly over lane bits 4..5 (16, 32)
#pragma unroll
    for (int i = 0; i < 8; ++i) {
        acc[i] += __shfl_xor(acc[i], 16);
        acc[i] += __shfl_xor(acc[i], 32);
    }
    if (lane < 16) {
        // self term
        uint4 sv = hb4[(size_t)node * 16 + lane];
        acc[0] += __uint_as_float(sv.x << 16); acc[1] += __uint_as_float(sv.x & 0xFFFF0000u);
        acc[2] += __uint_as_float(sv.y << 16); acc[3] += __uint_as_float(sv.y & 0xFFFF0000u);
        acc[4] += __uint_as_float(sv.z << 16); acc[5] += __uint_as_float(sv.z & 0xFFFF0000u);
        acc[6] += __uint_as_float(sv.w << 16); acc[7] += __uint_as_float(sv.w & 0xFFFF0000u);
        float dn = dinv[node];
        float4 b0 = ((const float4*)bias)[lane * 2];
        float4 b1 = ((const float4*)bias)[lane * 2 + 1];
        float r[8];
        r[0] = dn * acc[0] + b0.x; r[1] = dn * acc[1] + b0.y;
        r[2] = dn * acc[2] + b0.z; r[3] = dn * acc[3] + b0.w;
        r[4] = dn * acc[4] + b1.x; r[5] = dn * acc[5] + b1.y;
        r[6] = dn * acc[6] + b1.z; r[7] = dn * acc[7] + b1.w;
        if (doGelu) {
#pragma unroll
            for (int i = 0; i < 8; ++i) r[i] = gelu_f(r[i]);
        }
        float4 o0 = make_float4(r[0], r[1], r[2], r[3]);
        float4 o1 = make_float4(r[4], r[5], r[6], r[7]);
        ((float4*)out)[(size_t)node * 32 + lane * 2]     = o0;
        ((float4*)out)[(size_t)node * 32 + lane * 2 + 1] = o1;
    }
}

// ---------------- launch ----------------

extern "C" void kernel_launch(void* const* d_in, const int* in_sizes, int n_in,
                              void* d_out, int out_size, void* d_ws, size_t ws_size,
                              hipStream_t stream) {
    const float* X  = (const float*)d_in[0];
    const int*   EI = (const int*)d_in[1];
    const float* Wp = (const float*)d_in[2];
    const float* bp = (const float*)d_in[3];
    float* OUT = (float*)d_out;

    int N = in_sizes[0] / D;
    int E = in_sizes[1] / 2;
    int L = in_sizes[3] / D;
    const int* src = EI;
    const int* dst = EI + E;

    char* w = (char*)d_ws;
    auto alloc = [&](size_t bytes) {
        char* p = w;
        w += (bytes + 255) & ~(size_t)255;
        return p;
    };
    unsigned short* HB = (unsigned short*)alloc((size_t)N * D * sizeof(unsigned short)); // 12.8 MB
    float* XB   = (float*)alloc((size_t)N * D * sizeof(float));   // 25.6 MB
    float* DINV = (float*)alloc((size_t)N * sizeof(float));
    int*   RP   = (int*)alloc((size_t)(N + 1) * sizeof(int));
    int*   CNT  = (int*)alloc((size_t)N * sizeof(int));
    int*   BSUM = (int*)alloc(4096 * sizeof(int));
    unsigned short* RANK = (unsigned short*)alloc((size_t)E * sizeof(unsigned short));
    unsigned short* SSRC = (unsigned short*)alloc(((size_t)E + 64) * sizeof(unsigned short));
    short* BFH  = (short*)alloc((size_t)L * D * D * sizeof(short));
    short* BFL  = (short*)alloc((size_t)L * D * D * sizeof(short));
    (void)ws_size; (void)n_in; (void)out_size;

    zero_k<<<(N + 255) / 256, 256, 0, stream>>>(CNT, N);

    int eb = (E + 255) / 256;
    rank_k<<<eb, 256, 0, stream>>>(dst, E, CNT, RANK);
    int nb = (N + 1023) / 1024;
    scan_a<<<nb, 1024, 0, stream>>>(CNT, N, RP, BSUM);
    scan_c<<<(N + 255) / 256, 256, 0, stream>>>(CNT, RP, BSUM, DINV, N, E);
    fill_k<<<eb, 256, 0, stream>>>(src, dst, RANK, RP, E, SSRC);

    int wtot = L * D * D;
    wsplit_k<<<(wtot + 255) / 256, 256, 0, stream>>>(Wp, BFH, BFL, wtot);

    int gb = (N + 63) / 64;
    int ab = (N + 3) / 4;
    for (int l = 0; l < L; ++l) {
        const float* xin = (l == 0) ? X : XB;
        gemm_k<<<gb, 256, 0, stream>>>(xin, BFH + (size_t)l * D * D, BFL + (size_t)l * D * D,
                                       DINV, HB, N);
        float* o = (l == L - 1) ? OUT : XB;
        agg_k<<<ab, 256, 0, stream>>>(HB, RP, SSRC, DINV, bp + (size_t)l * D, o, N,
                                      (l == L - 1) ? 1 : 0);
    }
}